// Round 5
// baseline (655.363 us; speedup 1.0000x reference)
//
#include <hip/hip_runtime.h>

#define N_NODES 50000
#define N_EDGES 1600000
#define IN_FEATS 512
#define N_HIDDEN 128
#define N_CLASSES 40
#define NBKT 782      // ceil(50000/64) buckets of 64 nodes
#define NBLK 800      // partition blocks
#define EPB 2000      // edges per partition block (800*2000 = 1.6M exact)

typedef __attribute__((ext_vector_type(8))) short bf16x8;
typedef __attribute__((ext_vector_type(4))) float f32x4;

__device__ __forceinline__ unsigned short f2bf(float f) {
    unsigned u = __float_as_uint(f);
    u = (u + 0x7FFFu + ((u >> 16) & 1u)) >> 16;   // round-to-nearest-even
    return (unsigned short)u;
}
__device__ __forceinline__ float bf2f(unsigned short h) {
    return __uint_as_float(((unsigned)h) << 16);
}

// ---------------------------------------------------------------------------
// P1: per-block LDS histograms by dst-bucket and src-bucket. No global atomics.
__global__ __launch_bounds__(256) void p1_hist(
    const int* __restrict__ src, const int* __restrict__ dst,
    int* __restrict__ histD, int* __restrict__ histS) {
    __shared__ int hd[NBKT], hs[NBKT];
    int t = threadIdx.x, b = blockIdx.x;
    for (int i = t; i < NBKT; i += 256) { hd[i] = 0; hs[i] = 0; }
    __syncthreads();
    int e0 = b * EPB;
    for (int i = t; i < EPB; i += 256) {
        atomicAdd(&hd[dst[e0 + i] >> 6], 1);
        atomicAdd(&hs[src[e0 + i] >> 6], 1);
    }
    __syncthreads();
    for (int i = t; i < NBKT; i += 256) {
        histD[b * NBKT + i] = hd[i];
        histS[b * NBKT + i] = hs[i];
    }
}

// ---------------------------------------------------------------------------
// P2: single-block scan -> bucket bases + per-(block,bucket) scatter bases.
__global__ __launch_bounds__(1024) void p2_scan(
    const int* __restrict__ histD, const int* __restrict__ histS,
    int* __restrict__ baseD, int* __restrict__ baseS,
    int* __restrict__ bucket_base, int* __restrict__ srcb_base,
    int* __restrict__ offsets) {
    __shared__ int part[1024];
    int t = threadIdx.x;
    // ---- dst side ----
    int tot = 0;
    if (t < NBKT)
        for (int blk = 0; blk < NBLK; blk++) tot += histD[blk * NBKT + t];
    part[t] = tot;
    __syncthreads();
    for (int off = 1; off < 1024; off <<= 1) {
        int v = (t >= off) ? part[t - off] : 0;
        __syncthreads();
        part[t] += v;
        __syncthreads();
    }
    if (t < NBKT) {
        int run = part[t] - tot;           // exclusive prefix
        bucket_base[t] = run;
        for (int blk = 0; blk < NBLK; blk++) {
            baseD[blk * NBKT + t] = run;
            run += histD[blk * NBKT + t];
        }
    }
    if (t == 0) { bucket_base[NBKT] = N_EDGES; offsets[N_NODES] = N_EDGES; }
    __syncthreads();
    // ---- src side ----
    tot = 0;
    if (t < NBKT)
        for (int blk = 0; blk < NBLK; blk++) tot += histS[blk * NBKT + t];
    part[t] = tot;
    __syncthreads();
    for (int off = 1; off < 1024; off <<= 1) {
        int v = (t >= off) ? part[t - off] : 0;
        __syncthreads();
        part[t] += v;
        __syncthreads();
    }
    if (t < NBKT) {
        int run = part[t] - tot;
        srcb_base[t] = run;
        for (int blk = 0; blk < NBLK; blk++) {
            baseS[blk * NBKT + t] = run;
            run += histS[blk * NBKT + t];
        }
    }
    if (t == 0) srcb_base[NBKT] = N_EDGES;
}

// ---------------------------------------------------------------------------
// P3: scatter edges into bucket-partitioned arrays via LDS cursors.
// edata = src (16b) | (dst&63)<<16 ; srcv = src&63 (byte).
__global__ __launch_bounds__(256) void p3_scatter(
    const int* __restrict__ src, const int* __restrict__ dst,
    const int* __restrict__ baseD, const int* __restrict__ baseS,
    unsigned int* __restrict__ edata, unsigned char* __restrict__ srcv) {
    __shared__ int curD[NBKT], curS[NBKT];
    int t = threadIdx.x, b = blockIdx.x;
    for (int i = t; i < NBKT; i += 256) {
        curD[i] = baseD[b * NBKT + i];
        curS[i] = baseS[b * NBKT + i];
    }
    __syncthreads();
    int e0 = b * EPB;
    for (int i = t; i < EPB; i += 256) {
        int s = src[e0 + i], d = dst[e0 + i];
        int slotD = atomicAdd(&curD[d >> 6], 1);
        edata[slotD] = (unsigned)s | ((unsigned)(d & 63) << 16);
        int slotS = atomicAdd(&curS[s >> 6], 1);
        srcv[slotS] = (unsigned char)(s & 63);
    }
}

// ---------------------------------------------------------------------------
// P4count: exact out-degree per node from src-bucketed bytes -> norm_src.
__global__ __launch_bounds__(256) void p4_count(
    const int* __restrict__ srcb_base, const unsigned char* __restrict__ srcv,
    float* __restrict__ norm_src) {
    __shared__ int cnt[64];
    int t = threadIdx.x, b = blockIdx.x;
    if (t < 64) cnt[t] = 0;
    __syncthreads();
    int s0 = srcb_base[b], s1 = srcb_base[b + 1];
    for (int i = s0 + t; i < s1; i += 256) atomicAdd(&cnt[srcv[i]], 1);
    __syncthreads();
    if (t < 64) {
        int node = b * 64 + t;
        if (node < N_NODES) norm_src[node] = rsqrtf(fmaxf((float)cnt[t], 1.0f));
    }
}

// ---------------------------------------------------------------------------
// P4build: per dst-bucket exact CSR (offsets + sorted_src) + norm_dst.
__global__ __launch_bounds__(256) void p4_build(
    const int* __restrict__ bucket_base, const unsigned int* __restrict__ edata,
    int* __restrict__ offsets, float* __restrict__ norm_dst,
    int* __restrict__ sorted_src) {
    __shared__ int cnt[64], cur[64];
    int t = threadIdx.x, b = blockIdx.x;
    if (t < 64) cnt[t] = 0;
    __syncthreads();
    int s0 = bucket_base[b], s1 = bucket_base[b + 1];
    for (int i = s0 + t; i < s1; i += 256)
        atomicAdd(&cnt[(edata[i] >> 16) & 63], 1);
    __syncthreads();
    if (t == 0) {
        int run = 0;
        for (int i = 0; i < 64; i++) { cur[i] = run; run += cnt[i]; }
    }
    __syncthreads();
    if (t < 64) {
        int node = b * 64 + t;
        if (node < N_NODES) {
            offsets[node] = s0 + cur[t];
            norm_dst[node] = rsqrtf(fmaxf((float)cnt[t], 1.0f));
        }
    }
    __syncthreads();
    for (int i = s0 + t; i < s1; i += 256) {
        unsigned e = edata[i];
        int slot = atomicAdd(&cur[(e >> 16) & 63], 1);
        sorted_src[s0 + slot] = (int)(e & 0xFFFFu);
    }
}

// ---------------------------------------------------------------------------
// pre-convert W1 [512][128] -> transposed bf16 hi/lo [col][k]
__global__ __launch_bounds__(256) void w1cvt_kernel(const float* __restrict__ W1,
                                                    unsigned short* __restrict__ Wth,
                                                    unsigned short* __restrict__ Wtl) {
    int i = blockIdx.x * 256 + threadIdx.x;
    if (i >= IN_FEATS * N_HIDDEN) return;
    int k = i >> 7, c = i & 127;
    float v = W1[i];
    unsigned short h = f2bf(v);
    Wth[c * IN_FEATS + k] = h;
    Wtl[c * IN_FEATS + k] = f2bf(v - bf2f(h));
}

// ---------------------------------------------------------------------------
// GEMM1 via bf16 MFMA, split-precision (xh*wh + xh*wl + xl*wh).
// Block tile 128x128, BK=32, 4 waves in 2x2 grid. Output H in bf16.
__global__ __launch_bounds__(256) void gemm1_kernel(
    const float* __restrict__ X, const unsigned short* __restrict__ Wth,
    const unsigned short* __restrict__ Wtl,
    const float* __restrict__ norm_src, unsigned short* __restrict__ Hb) {
    __shared__ __align__(16) unsigned short Xh[128][40];
    __shared__ __align__(16) unsigned short Xl[128][40];
    __shared__ __align__(16) unsigned short Wh[128][40];
    __shared__ __align__(16) unsigned short Wl[128][40];
    const int tid = threadIdx.x;
    const int lane = tid & 63;
    const int wave = tid >> 6;
    const int wr = (wave & 1) * 64;
    const int wc = (wave >> 1) * 64;
    const int row0 = blockIdx.x * 128;
    const int m = lane & 15;
    const int q = lane >> 4;

    f32x4 acc[4][4];
#pragma unroll
    for (int i = 0; i < 4; i++)
#pragma unroll
        for (int j = 0; j < 4; j++) acc[i][j] = (f32x4){0.f, 0.f, 0.f, 0.f};

    for (int k0 = 0; k0 < IN_FEATS; k0 += 32) {
#pragma unroll
        for (int l = 0; l < 4; l++) {
            int s = tid + l * 256;
            int r = s >> 3;
            int kq = (s & 7) * 4;
            float4 v = make_float4(0.f, 0.f, 0.f, 0.f);
            int grow = row0 + r;
            if (grow < N_NODES) v = *(const float4*)&X[(size_t)grow * IN_FEATS + k0 + kq];
            unsigned short h0 = f2bf(v.x), h1 = f2bf(v.y), h2 = f2bf(v.z), h3 = f2bf(v.w);
            unsigned short l0 = f2bf(v.x - bf2f(h0)), l1 = f2bf(v.y - bf2f(h1));
            unsigned short l2 = f2bf(v.z - bf2f(h2)), l3 = f2bf(v.w - bf2f(h3));
            uint2 ph = make_uint2((unsigned)h0 | ((unsigned)h1 << 16),
                                  (unsigned)h2 | ((unsigned)h3 << 16));
            uint2 pl = make_uint2((unsigned)l0 | ((unsigned)l1 << 16),
                                  (unsigned)l2 | ((unsigned)l3 << 16));
            *(uint2*)&Xh[r][kq] = ph;
            *(uint2*)&Xl[r][kq] = pl;
        }
#pragma unroll
        for (int l = 0; l < 2; l++) {
            int s = tid + l * 256;
            int c = s >> 2;
            int kq = (s & 3) * 8;
            *(uint4*)&Wh[c][kq] = *(const uint4*)&Wth[(size_t)c * IN_FEATS + k0 + kq];
            *(uint4*)&Wl[c][kq] = *(const uint4*)&Wtl[(size_t)c * IN_FEATS + k0 + kq];
        }
        __syncthreads();

        bf16x8 ah[4], al[4], bh[4], bl[4];
#pragma unroll
        for (int i = 0; i < 4; i++) {
            ah[i] = *(const bf16x8*)&Xh[wr + i * 16 + m][q * 8];
            al[i] = *(const bf16x8*)&Xl[wr + i * 16 + m][q * 8];
            bh[i] = *(const bf16x8*)&Wh[wc + i * 16 + m][q * 8];
            bl[i] = *(const bf16x8*)&Wl[wc + i * 16 + m][q * 8];
        }
#pragma unroll
        for (int i = 0; i < 4; i++)
#pragma unroll
            for (int j = 0; j < 4; j++) {
                acc[i][j] = __builtin_amdgcn_mfma_f32_16x16x32_bf16(ah[i], bh[j], acc[i][j], 0, 0, 0);
                acc[i][j] = __builtin_amdgcn_mfma_f32_16x16x32_bf16(ah[i], bl[j], acc[i][j], 0, 0, 0);
                acc[i][j] = __builtin_amdgcn_mfma_f32_16x16x32_bf16(al[i], bh[j], acc[i][j], 0, 0, 0);
            }
        __syncthreads();
    }
    // epilogue: C/D layout col=lane&15, row=(lane>>4)*4+reg; store bf16
#pragma unroll
    for (int i = 0; i < 4; i++) {
#pragma unroll
        for (int r = 0; r < 4; r++) {
            int grow = row0 + wr + i * 16 + q * 4 + r;
            if (grow < N_NODES) {
                float sc = norm_src[grow];
#pragma unroll
                for (int j = 0; j < 4; j++)
                    Hb[(size_t)grow * N_HIDDEN + wc + j * 16 + m] = f2bf(acc[i][j][r] * sc);
            }
        }
    }
}

// ---------------------------------------------------------------------------
// agg1: one wave per dst node; 4 edges x 16 lanes x bf16x8 (uint4) per step,
// unroll 2, f32 accum, xor-16/32 butterfly, fused norm+bias+relu.
#define ADD8(W)                                               \
    acc0 += __uint_as_float((W).x << 16);                     \
    acc1 += __uint_as_float((W).x & 0xffff0000u);             \
    acc2 += __uint_as_float((W).y << 16);                     \
    acc3 += __uint_as_float((W).y & 0xffff0000u);             \
    acc4 += __uint_as_float((W).z << 16);                     \
    acc5 += __uint_as_float((W).z & 0xffff0000u);             \
    acc6 += __uint_as_float((W).w << 16);                     \
    acc7 += __uint_as_float((W).w & 0xffff0000u);

__global__ __launch_bounds__(256) void agg1_kernel(
    const int* __restrict__ offsets, const int* __restrict__ sorted_src,
    const unsigned short* __restrict__ Hb, const float* __restrict__ norm_dst,
    const float* __restrict__ b1, float* __restrict__ H1) {
    int wid = (blockIdx.x * 256 + threadIdx.x) >> 6;
    int lane = threadIdx.x & 63;
    if (wid >= N_NODES) return;
    int start = offsets[wid], end = offsets[wid + 1];
    int quad = lane >> 4;
    int c8 = (lane & 15) * 8;
    float acc0 = 0.f, acc1 = 0.f, acc2 = 0.f, acc3 = 0.f;
    float acc4 = 0.f, acc5 = 0.f, acc6 = 0.f, acc7 = 0.f;
    int base = start;
    for (; base + 8 <= end; base += 8) {
        int e0 = sorted_src[base + quad];
        int e1 = sorted_src[base + 4 + quad];
        uint4 w0 = *(const uint4*)&Hb[(size_t)e0 * N_HIDDEN + c8];
        uint4 w1 = *(const uint4*)&Hb[(size_t)e1 * N_HIDDEN + c8];
        ADD8(w0);
        ADD8(w1);
    }
    int rem = end - base;
    if (quad < rem) {
        int e = sorted_src[base + quad];
        uint4 w = *(const uint4*)&Hb[(size_t)e * N_HIDDEN + c8];
        ADD8(w);
    }
    if (quad + 4 < rem) {
        int e = sorted_src[base + 4 + quad];
        uint4 w = *(const uint4*)&Hb[(size_t)e * N_HIDDEN + c8];
        ADD8(w);
    }
    acc0 += __shfl_xor(acc0, 16); acc0 += __shfl_xor(acc0, 32);
    acc1 += __shfl_xor(acc1, 16); acc1 += __shfl_xor(acc1, 32);
    acc2 += __shfl_xor(acc2, 16); acc2 += __shfl_xor(acc2, 32);
    acc3 += __shfl_xor(acc3, 16); acc3 += __shfl_xor(acc3, 32);
    acc4 += __shfl_xor(acc4, 16); acc4 += __shfl_xor(acc4, 32);
    acc5 += __shfl_xor(acc5, 16); acc5 += __shfl_xor(acc5, 32);
    acc6 += __shfl_xor(acc6, 16); acc6 += __shfl_xor(acc6, 32);
    acc7 += __shfl_xor(acc7, 16); acc7 += __shfl_xor(acc7, 32);
    if (quad == 0) {
        float nd = norm_dst[wid];
        float4 ba = *(const float4*)&b1[c8];
        float4 bb = *(const float4*)&b1[c8 + 4];
        float4 o0 = make_float4(fmaxf(acc0 * nd + ba.x, 0.f), fmaxf(acc1 * nd + ba.y, 0.f),
                                fmaxf(acc2 * nd + ba.z, 0.f), fmaxf(acc3 * nd + ba.w, 0.f));
        float4 o1 = make_float4(fmaxf(acc4 * nd + bb.x, 0.f), fmaxf(acc5 * nd + bb.y, 0.f),
                                fmaxf(acc6 * nd + bb.z, 0.f), fmaxf(acc7 * nd + bb.w, 0.f));
        *(float4*)&H1[(size_t)wid * N_HIDDEN + c8] = o0;
        *(float4*)&H1[(size_t)wid * N_HIDDEN + c8 + 4] = o1;
    }
}

// ---------------------------------------------------------------------------
// GEMM2: H2p[n][0:40] = (H1[n,0:128] @ W2) * norm_src[n]; pitch-64 padded out.
__global__ __launch_bounds__(256) void gemm2_kernel(
    const float* __restrict__ H1, const float* __restrict__ W2,
    const float* __restrict__ norm_src, float* __restrict__ H2p) {
    __shared__ float Ws[N_HIDDEN * N_CLASSES + 64];
    int tid = threadIdx.x;
    for (int i = tid; i < N_HIDDEN * N_CLASSES; i += 256) Ws[i] = W2[i];
    __syncthreads();
    int wave = tid >> 6;
    int lane = tid & 63;
    int row = blockIdx.x * 4 + wave;
    if (row >= N_NODES) return;
    const float* h = &H1[(size_t)row * N_HIDDEN];
    float a0 = 0.f, a1 = 0.f, a2 = 0.f, a3 = 0.f;
#pragma unroll
    for (int k = 0; k < N_HIDDEN; k += 4) {
        float4 hv = *(const float4*)&h[k];
        a0 = fmaf(hv.x, Ws[(k + 0) * N_CLASSES + lane], a0);
        a1 = fmaf(hv.y, Ws[(k + 1) * N_CLASSES + lane], a1);
        a2 = fmaf(hv.z, Ws[(k + 2) * N_CLASSES + lane], a2);
        a3 = fmaf(hv.w, Ws[(k + 3) * N_CLASSES + lane], a3);
    }
    if (lane < N_CLASSES)
        H2p[(size_t)row * 64 + lane] = ((a0 + a1) + (a2 + a3)) * norm_src[row];
}

// ---------------------------------------------------------------------------
// agg2: one wave per dst node; 4 edges x 16 lanes x float4, unroll 2.
__global__ __launch_bounds__(256) void agg2_kernel(
    const int* __restrict__ offsets, const int* __restrict__ sorted_src,
    const float* __restrict__ H2p, const float* __restrict__ norm_dst,
    const float* __restrict__ b2, float* __restrict__ OUT) {
    int wid = (blockIdx.x * 256 + threadIdx.x) >> 6;
    int lane = threadIdx.x & 63;
    if (wid >= N_NODES) return;
    int start = offsets[wid], end = offsets[wid + 1];
    int quad = lane >> 4;
    int c4 = (lane & 15) * 4;
    bool active = c4 < N_CLASSES;
    float4 acc = make_float4(0.f, 0.f, 0.f, 0.f);
    int base = start;
    int nfull = (end - start) & ~7;
    for (; base < start + nfull; base += 8) {
        int e0 = sorted_src[base + quad];
        int e1 = sorted_src[base + 4 + quad];
        if (active) {
            float4 v0 = *(const float4*)&H2p[(size_t)e0 * 64 + c4];
            float4 v1 = *(const float4*)&H2p[(size_t)e1 * 64 + c4];
            acc.x += v0.x + v1.x;
            acc.y += v0.y + v1.y;
            acc.z += v0.z + v1.z;
            acc.w += v0.w + v1.w;
        }
    }
    int rem = end - base;
    int n4 = rem & ~3;
    for (int t = 0; t < n4; t += 4) {
        int e = sorted_src[base + t + quad];
        if (active) {
            float4 v = *(const float4*)&H2p[(size_t)e * 64 + c4];
            acc.x += v.x; acc.y += v.y; acc.z += v.z; acc.w += v.w;
        }
    }
    base += n4;
    if (quad < end - base && active) {
        int e = sorted_src[base + quad];
        float4 v = *(const float4*)&H2p[(size_t)e * 64 + c4];
        acc.x += v.x; acc.y += v.y; acc.z += v.z; acc.w += v.w;
    }
    acc.x += __shfl_xor(acc.x, 16); acc.x += __shfl_xor(acc.x, 32);
    acc.y += __shfl_xor(acc.y, 16); acc.y += __shfl_xor(acc.y, 32);
    acc.z += __shfl_xor(acc.z, 16); acc.z += __shfl_xor(acc.z, 32);
    acc.w += __shfl_xor(acc.w, 16); acc.w += __shfl_xor(acc.w, 32);
    if (lane < 10) {
        float nd = norm_dst[wid];
        float4 b = *(const float4*)&b2[lane * 4];
        acc.x = acc.x * nd + b.x;
        acc.y = acc.y * nd + b.y;
        acc.z = acc.z * nd + b.z;
        acc.w = acc.w * nd + b.w;
        *(float4*)&OUT[(size_t)wid * N_CLASSES + lane * 4] = acc;
    }
}

// ---------------------------------------------------------------------------
extern "C" void kernel_launch(void* const* d_in, const int* in_sizes, int n_in,
                              void* d_out, int out_size, void* d_ws, size_t ws_size,
                              hipStream_t stream) {
    const float* X   = (const float*)d_in[0];
    const float* W1  = (const float*)d_in[1];
    const float* b1  = (const float*)d_in[2];
    const float* W2  = (const float*)d_in[3];
    const float* b2  = (const float*)d_in[4];
    const int*   src = (const int*)d_in[5];
    const int*   dst = (const int*)d_in[6];
    float* out = (float*)d_out;

    // workspace layout (4B units). regionA (3.2M dwords) time-shared:
    //   phase 1: histD|histS|baseD|baseS (4 x 625600)   [dead after P3]
    //   phase 2: Hb bf16 50000x128 (1.6M dwords)        [dead after agg1]
    //   phase 3: H2p f32 50000x64 (3.2M dwords)
    float* norm_src   = (float*)d_ws;                     // 50000
    float* norm_dst   = norm_src + N_NODES;               // 50000
    int*   offsets    = (int*)(norm_dst + N_NODES);       // 50016 (incl pad)
    int*   bucket_base = offsets + N_NODES + 16;          // 800
    int*   srcb_base  = bucket_base + 800;                // 800
    unsigned int* edata = (unsigned int*)(srcb_base + 800);       // 1.6M
    unsigned char* srcv = (unsigned char*)(edata + N_EDGES);      // 1.6MB (400K dw)
    int*   sorted_src = (int*)(edata + N_EDGES) + 400000; // 1.6M
    int*   regionA    = sorted_src + N_EDGES;             // 3.2M
    int*   histD      = regionA;
    int*   histS      = regionA + 625600;
    int*   baseD      = regionA + 1251200;
    int*   baseS      = regionA + 1876800;
    unsigned short* Hb = (unsigned short*)regionA;
    float* H2p        = (float*)regionA;
    float* H1         = (float*)(regionA + 3200000);      // 1.6M
    unsigned short* W1th = (unsigned short*)(H1 + (size_t)N_NODES * N_HIDDEN);
    unsigned short* W1tl = W1th + IN_FEATS * N_HIDDEN;

    p1_hist<<<NBLK, 256, 0, stream>>>(src, dst, histD, histS);
    p2_scan<<<1, 1024, 0, stream>>>(histD, histS, baseD, baseS,
                                    bucket_base, srcb_base, offsets);
    p3_scatter<<<NBLK, 256, 0, stream>>>(src, dst, baseD, baseS, edata, srcv);
    p4_count<<<NBKT, 256, 0, stream>>>(srcb_base, srcv, norm_src);
    p4_build<<<NBKT, 256, 0, stream>>>(bucket_base, edata, offsets, norm_dst, sorted_src);

    w1cvt_kernel<<<(IN_FEATS * N_HIDDEN + 255) / 256, 256, 0, stream>>>(W1, W1th, W1tl);
    gemm1_kernel<<<(N_NODES + 127) / 128, 256, 0, stream>>>(X, W1th, W1tl, norm_src, Hb);
    agg1_kernel<<<(N_NODES + 3) / 4, 256, 0, stream>>>(offsets, sorted_src, Hb, norm_dst, b1, H1);
    gemm2_kernel<<<(N_NODES + 3) / 4, 256, 0, stream>>>(H1, W2, norm_src, H2p);
    agg2_kernel<<<(N_NODES + 3) / 4, 256, 0, stream>>>(offsets, sorted_src, H2p, norm_dst, b2, out);
}

// Round 6
// 483.861 us; speedup vs baseline: 1.3544x; 1.3544x over previous
//
#include <hip/hip_runtime.h>

#define N_NODES 50000
#define N_EDGES 1600000
#define IN_FEATS 512
#define N_HIDDEN 128
#define N_CLASSES 40
#define NBKT 782      // ceil(50000/64) buckets of 64 nodes
#define NBLK 800      // partition blocks
#define EPB 2000      // edges per partition block (800*2000 = 1.6M exact)

typedef __attribute__((ext_vector_type(8))) short bf16x8;
typedef __attribute__((ext_vector_type(4))) float f32x4;

__device__ __forceinline__ unsigned short f2bf(float f) {
    unsigned u = __float_as_uint(f);
    u = (u + 0x7FFFu + ((u >> 16) & 1u)) >> 16;   // round-to-nearest-even
    return (unsigned short)u;
}
__device__ __forceinline__ float bf2f(unsigned short h) {
    return __uint_as_float(((unsigned)h) << 16);
}

// ---------------------------------------------------------------------------
// P1: per-block LDS histograms by dst-bucket and src-bucket. No global atomics.
__global__ __launch_bounds__(256) void p1_hist(
    const int* __restrict__ src, const int* __restrict__ dst,
    int* __restrict__ histD, int* __restrict__ histS) {
    __shared__ int hd[NBKT], hs[NBKT];
    int t = threadIdx.x, b = blockIdx.x;
    for (int i = t; i < NBKT; i += 256) { hd[i] = 0; hs[i] = 0; }
    __syncthreads();
    int e0 = b * EPB;
    for (int i = t; i < EPB; i += 256) {
        atomicAdd(&hd[dst[e0 + i] >> 6], 1);
        atomicAdd(&hs[src[e0 + i] >> 6], 1);
    }
    __syncthreads();
    for (int i = t; i < NBKT; i += 256) {
        histD[b * NBKT + i] = hd[i];
        histS[b * NBKT + i] = hs[i];
    }
}

// ---------------------------------------------------------------------------
// P2a: one wave per bucket — parallel scan over the 800-block dimension.
// baseD/baseS get the LOCAL (within-bucket) exclusive prefix; totals out.
__global__ __launch_bounds__(256) void p2_local(
    const int* __restrict__ histD, const int* __restrict__ histS,
    int* __restrict__ baseD, int* __restrict__ baseS,
    int* __restrict__ totD, int* __restrict__ totS) {
    int wv = threadIdx.x >> 6, lane = threadIdx.x & 63;
    int w = blockIdx.x * 4 + wv;
    if (w >= NBKT) return;
    int runD = 0, runS = 0;
#pragma unroll
    for (int c = 0; c < 13; c++) {
        int blk = c * 64 + lane;
        int vD = 0, vS = 0;
        if (blk < NBLK) {
            vD = histD[blk * NBKT + w];
            vS = histS[blk * NBKT + w];
        }
        int iD = vD, iS = vS;
#pragma unroll
        for (int off = 1; off < 64; off <<= 1) {
            int tD = __shfl_up(iD, off);
            int tS = __shfl_up(iS, off);
            if (lane >= off) { iD += tD; iS += tS; }
        }
        if (blk < NBLK) {
            baseD[blk * NBKT + w] = runD + iD - vD;
            baseS[blk * NBKT + w] = runS + iS - vS;
        }
        runD += __shfl(iD, 63);
        runS += __shfl(iS, 63);
    }
    if (lane == 0) { totD[w] = runD; totS[w] = runS; }
}

// P2b: single-block scan over the 782 bucket totals only.
__global__ __launch_bounds__(1024) void p2_small(
    const int* __restrict__ totD, const int* __restrict__ totS,
    int* __restrict__ bucket_base, int* __restrict__ srcb_base,
    int* __restrict__ offsets) {
    __shared__ int part[1024];
    int t = threadIdx.x;
    int v = (t < NBKT) ? totD[t] : 0;
    part[t] = v;
    __syncthreads();
    for (int off = 1; off < 1024; off <<= 1) {
        int x = (t >= off) ? part[t - off] : 0;
        __syncthreads();
        part[t] += x;
        __syncthreads();
    }
    if (t < NBKT) bucket_base[t] = part[t] - v;
    if (t == 0) { bucket_base[NBKT] = N_EDGES; offsets[N_NODES] = N_EDGES; }
    __syncthreads();
    v = (t < NBKT) ? totS[t] : 0;
    part[t] = v;
    __syncthreads();
    for (int off = 1; off < 1024; off <<= 1) {
        int x = (t >= off) ? part[t - off] : 0;
        __syncthreads();
        part[t] += x;
        __syncthreads();
    }
    if (t < NBKT) srcb_base[t] = part[t] - v;
    if (t == 0) srcb_base[NBKT] = N_EDGES;
}

// ---------------------------------------------------------------------------
// P3: scatter edges into bucket-partitioned arrays via LDS cursors.
// edata = src (16b) | (dst&63)<<16 ; srcv = src&63 (byte).
__global__ __launch_bounds__(256) void p3_scatter(
    const int* __restrict__ src, const int* __restrict__ dst,
    const int* __restrict__ baseD, const int* __restrict__ baseS,
    const int* __restrict__ bucket_base, const int* __restrict__ srcb_base,
    unsigned int* __restrict__ edata, unsigned char* __restrict__ srcv) {
    __shared__ int curD[NBKT], curS[NBKT];
    int t = threadIdx.x, b = blockIdx.x;
    for (int i = t; i < NBKT; i += 256) {
        curD[i] = bucket_base[i] + baseD[b * NBKT + i];
        curS[i] = srcb_base[i] + baseS[b * NBKT + i];
    }
    __syncthreads();
    int e0 = b * EPB;
    for (int i = t; i < EPB; i += 256) {
        int s = src[e0 + i], d = dst[e0 + i];
        int slotD = atomicAdd(&curD[d >> 6], 1);
        edata[slotD] = (unsigned)s | ((unsigned)(d & 63) << 16);
        int slotS = atomicAdd(&curS[s >> 6], 1);
        srcv[slotS] = (unsigned char)(s & 63);
    }
}

// ---------------------------------------------------------------------------
// P4count: exact out-degree per node from src-bucketed bytes -> norm_src.
__global__ __launch_bounds__(256) void p4_count(
    const int* __restrict__ srcb_base, const unsigned char* __restrict__ srcv,
    float* __restrict__ norm_src) {
    __shared__ int cnt[64];
    int t = threadIdx.x, b = blockIdx.x;
    if (t < 64) cnt[t] = 0;
    __syncthreads();
    int s0 = srcb_base[b], s1 = srcb_base[b + 1];
    for (int i = s0 + t; i < s1; i += 256) atomicAdd(&cnt[srcv[i]], 1);
    __syncthreads();
    if (t < 64) {
        int node = b * 64 + t;
        if (node < N_NODES) norm_src[node] = rsqrtf(fmaxf((float)cnt[t], 1.0f));
    }
}

// ---------------------------------------------------------------------------
// P4build: per dst-bucket exact CSR (offsets + sorted_src) + norm_dst.
__global__ __launch_bounds__(256) void p4_build(
    const int* __restrict__ bucket_base, const unsigned int* __restrict__ edata,
    int* __restrict__ offsets, float* __restrict__ norm_dst,
    int* __restrict__ sorted_src) {
    __shared__ int cnt[64], cur[64];
    int t = threadIdx.x, b = blockIdx.x;
    if (t < 64) cnt[t] = 0;
    __syncthreads();
    int s0 = bucket_base[b], s1 = bucket_base[b + 1];
    for (int i = s0 + t; i < s1; i += 256)
        atomicAdd(&cnt[(edata[i] >> 16) & 63], 1);
    __syncthreads();
    if (t == 0) {
        int run = 0;
        for (int i = 0; i < 64; i++) { cur[i] = run; run += cnt[i]; }
    }
    __syncthreads();
    if (t < 64) {
        int node = b * 64 + t;
        if (node < N_NODES) {
            offsets[node] = s0 + cur[t];
            norm_dst[node] = rsqrtf(fmaxf((float)cnt[t], 1.0f));
        }
    }
    __syncthreads();
    for (int i = s0 + t; i < s1; i += 256) {
        unsigned e = edata[i];
        int slot = atomicAdd(&cur[(e >> 16) & 63], 1);
        sorted_src[s0 + slot] = (int)(e & 0xFFFFu);
    }
}

// ---------------------------------------------------------------------------
// pre-convert W1 [512][128] -> transposed bf16 hi/lo [col][k]
__global__ __launch_bounds__(256) void w1cvt_kernel(const float* __restrict__ W1,
                                                    unsigned short* __restrict__ Wth,
                                                    unsigned short* __restrict__ Wtl) {
    int i = blockIdx.x * 256 + threadIdx.x;
    if (i >= IN_FEATS * N_HIDDEN) return;
    int k = i >> 7, c = i & 127;
    float v = W1[i];
    unsigned short h = f2bf(v);
    Wth[c * IN_FEATS + k] = h;
    Wtl[c * IN_FEATS + k] = f2bf(v - bf2f(h));
}

// ---------------------------------------------------------------------------
// GEMM1 via bf16 MFMA, split-precision (xh*wh + xh*wl + xl*wh).
// Block tile 128x128, BK=32, 4 waves in 2x2 grid. Output H in bf16.
__global__ __launch_bounds__(256) void gemm1_kernel(
    const float* __restrict__ X, const unsigned short* __restrict__ Wth,
    const unsigned short* __restrict__ Wtl,
    const float* __restrict__ norm_src, unsigned short* __restrict__ Hb) {
    __shared__ __align__(16) unsigned short Xh[128][40];
    __shared__ __align__(16) unsigned short Xl[128][40];
    __shared__ __align__(16) unsigned short Wh[128][40];
    __shared__ __align__(16) unsigned short Wl[128][40];
    const int tid = threadIdx.x;
    const int lane = tid & 63;
    const int wave = tid >> 6;
    const int wr = (wave & 1) * 64;
    const int wc = (wave >> 1) * 64;
    const int row0 = blockIdx.x * 128;
    const int m = lane & 15;
    const int q = lane >> 4;

    f32x4 acc[4][4];
#pragma unroll
    for (int i = 0; i < 4; i++)
#pragma unroll
        for (int j = 0; j < 4; j++) acc[i][j] = (f32x4){0.f, 0.f, 0.f, 0.f};

    for (int k0 = 0; k0 < IN_FEATS; k0 += 32) {
#pragma unroll
        for (int l = 0; l < 4; l++) {
            int s = tid + l * 256;
            int r = s >> 3;
            int kq = (s & 7) * 4;
            float4 v = make_float4(0.f, 0.f, 0.f, 0.f);
            int grow = row0 + r;
            if (grow < N_NODES) v = *(const float4*)&X[(size_t)grow * IN_FEATS + k0 + kq];
            unsigned short h0 = f2bf(v.x), h1 = f2bf(v.y), h2 = f2bf(v.z), h3 = f2bf(v.w);
            unsigned short l0 = f2bf(v.x - bf2f(h0)), l1 = f2bf(v.y - bf2f(h1));
            unsigned short l2 = f2bf(v.z - bf2f(h2)), l3 = f2bf(v.w - bf2f(h3));
            uint2 ph = make_uint2((unsigned)h0 | ((unsigned)h1 << 16),
                                  (unsigned)h2 | ((unsigned)h3 << 16));
            uint2 pl = make_uint2((unsigned)l0 | ((unsigned)l1 << 16),
                                  (unsigned)l2 | ((unsigned)l3 << 16));
            *(uint2*)&Xh[r][kq] = ph;
            *(uint2*)&Xl[r][kq] = pl;
        }
#pragma unroll
        for (int l = 0; l < 2; l++) {
            int s = tid + l * 256;
            int c = s >> 2;
            int kq = (s & 3) * 8;
            *(uint4*)&Wh[c][kq] = *(const uint4*)&Wth[(size_t)c * IN_FEATS + k0 + kq];
            *(uint4*)&Wl[c][kq] = *(const uint4*)&Wtl[(size_t)c * IN_FEATS + k0 + kq];
        }
        __syncthreads();

        bf16x8 ah[4], al[4], bh[4], bl[4];
#pragma unroll
        for (int i = 0; i < 4; i++) {
            ah[i] = *(const bf16x8*)&Xh[wr + i * 16 + m][q * 8];
            al[i] = *(const bf16x8*)&Xl[wr + i * 16 + m][q * 8];
            bh[i] = *(const bf16x8*)&Wh[wc + i * 16 + m][q * 8];
            bl[i] = *(const bf16x8*)&Wl[wc + i * 16 + m][q * 8];
        }
#pragma unroll
        for (int i = 0; i < 4; i++)
#pragma unroll
            for (int j = 0; j < 4; j++) {
                acc[i][j] = __builtin_amdgcn_mfma_f32_16x16x32_bf16(ah[i], bh[j], acc[i][j], 0, 0, 0);
                acc[i][j] = __builtin_amdgcn_mfma_f32_16x16x32_bf16(ah[i], bl[j], acc[i][j], 0, 0, 0);
                acc[i][j] = __builtin_amdgcn_mfma_f32_16x16x32_bf16(al[i], bh[j], acc[i][j], 0, 0, 0);
            }
        __syncthreads();
    }
    // epilogue: C/D layout col=lane&15, row=(lane>>4)*4+reg; store bf16
#pragma unroll
    for (int i = 0; i < 4; i++) {
#pragma unroll
        for (int r = 0; r < 4; r++) {
            int grow = row0 + wr + i * 16 + q * 4 + r;
            if (grow < N_NODES) {
                float sc = norm_src[grow];
#pragma unroll
                for (int j = 0; j < 4; j++)
                    Hb[(size_t)grow * N_HIDDEN + wc + j * 16 + m] = f2bf(acc[i][j][r] * sc);
            }
        }
    }
}

// ---------------------------------------------------------------------------
// agg1: one wave per dst node; 4 edges x 16 lanes x bf16x8 (uint4) per step,
// unroll 2, f32 accum, xor-16/32 butterfly, fused norm+bias+relu.
#define ADD8(W)                                               \
    acc0 += __uint_as_float((W).x << 16);                     \
    acc1 += __uint_as_float((W).x & 0xffff0000u);             \
    acc2 += __uint_as_float((W).y << 16);                     \
    acc3 += __uint_as_float((W).y & 0xffff0000u);             \
    acc4 += __uint_as_float((W).z << 16);                     \
    acc5 += __uint_as_float((W).z & 0xffff0000u);             \
    acc6 += __uint_as_float((W).w << 16);                     \
    acc7 += __uint_as_float((W).w & 0xffff0000u);

__global__ __launch_bounds__(256) void agg1_kernel(
    const int* __restrict__ offsets, const int* __restrict__ sorted_src,
    const unsigned short* __restrict__ Hb, const float* __restrict__ norm_dst,
    const float* __restrict__ b1, float* __restrict__ H1) {
    int wid = (blockIdx.x * 256 + threadIdx.x) >> 6;
    int lane = threadIdx.x & 63;
    if (wid >= N_NODES) return;
    int start = offsets[wid], end = offsets[wid + 1];
    int quad = lane >> 4;
    int c8 = (lane & 15) * 8;
    float acc0 = 0.f, acc1 = 0.f, acc2 = 0.f, acc3 = 0.f;
    float acc4 = 0.f, acc5 = 0.f, acc6 = 0.f, acc7 = 0.f;
    int base = start;
    for (; base + 8 <= end; base += 8) {
        int e0 = sorted_src[base + quad];
        int e1 = sorted_src[base + 4 + quad];
        uint4 w0 = *(const uint4*)&Hb[(size_t)e0 * N_HIDDEN + c8];
        uint4 w1 = *(const uint4*)&Hb[(size_t)e1 * N_HIDDEN + c8];
        ADD8(w0);
        ADD8(w1);
    }
    int rem = end - base;
    if (quad < rem) {
        int e = sorted_src[base + quad];
        uint4 w = *(const uint4*)&Hb[(size_t)e * N_HIDDEN + c8];
        ADD8(w);
    }
    if (quad + 4 < rem) {
        int e = sorted_src[base + 4 + quad];
        uint4 w = *(const uint4*)&Hb[(size_t)e * N_HIDDEN + c8];
        ADD8(w);
    }
    acc0 += __shfl_xor(acc0, 16); acc0 += __shfl_xor(acc0, 32);
    acc1 += __shfl_xor(acc1, 16); acc1 += __shfl_xor(acc1, 32);
    acc2 += __shfl_xor(acc2, 16); acc2 += __shfl_xor(acc2, 32);
    acc3 += __shfl_xor(acc3, 16); acc3 += __shfl_xor(acc3, 32);
    acc4 += __shfl_xor(acc4, 16); acc4 += __shfl_xor(acc4, 32);
    acc5 += __shfl_xor(acc5, 16); acc5 += __shfl_xor(acc5, 32);
    acc6 += __shfl_xor(acc6, 16); acc6 += __shfl_xor(acc6, 32);
    acc7 += __shfl_xor(acc7, 16); acc7 += __shfl_xor(acc7, 32);
    if (quad == 0) {
        float nd = norm_dst[wid];
        float4 ba = *(const float4*)&b1[c8];
        float4 bb = *(const float4*)&b1[c8 + 4];
        float4 o0 = make_float4(fmaxf(acc0 * nd + ba.x, 0.f), fmaxf(acc1 * nd + ba.y, 0.f),
                                fmaxf(acc2 * nd + ba.z, 0.f), fmaxf(acc3 * nd + ba.w, 0.f));
        float4 o1 = make_float4(fmaxf(acc4 * nd + bb.x, 0.f), fmaxf(acc5 * nd + bb.y, 0.f),
                                fmaxf(acc6 * nd + bb.z, 0.f), fmaxf(acc7 * nd + bb.w, 0.f));
        *(float4*)&H1[(size_t)wid * N_HIDDEN + c8] = o0;
        *(float4*)&H1[(size_t)wid * N_HIDDEN + c8 + 4] = o1;
    }
}

// ---------------------------------------------------------------------------
// GEMM2: H2p[n][0:40] = (H1[n,0:128] @ W2) * norm_src[n]; pitch-64 padded out.
__global__ __launch_bounds__(256) void gemm2_kernel(
    const float* __restrict__ H1, const float* __restrict__ W2,
    const float* __restrict__ norm_src, float* __restrict__ H2p) {
    __shared__ float Ws[N_HIDDEN * N_CLASSES + 64];
    int tid = threadIdx.x;
    for (int i = tid; i < N_HIDDEN * N_CLASSES; i += 256) Ws[i] = W2[i];
    __syncthreads();
    int wave = tid >> 6;
    int lane = tid & 63;
    int row = blockIdx.x * 4 + wave;
    if (row >= N_NODES) return;
    const float* h = &H1[(size_t)row * N_HIDDEN];
    float a0 = 0.f, a1 = 0.f, a2 = 0.f, a3 = 0.f;
#pragma unroll
    for (int k = 0; k < N_HIDDEN; k += 4) {
        float4 hv = *(const float4*)&h[k];
        a0 = fmaf(hv.x, Ws[(k + 0) * N_CLASSES + lane], a0);
        a1 = fmaf(hv.y, Ws[(k + 1) * N_CLASSES + lane], a1);
        a2 = fmaf(hv.z, Ws[(k + 2) * N_CLASSES + lane], a2);
        a3 = fmaf(hv.w, Ws[(k + 3) * N_CLASSES + lane], a3);
    }
    if (lane < N_CLASSES)
        H2p[(size_t)row * 64 + lane] = ((a0 + a1) + (a2 + a3)) * norm_src[row];
}

// ---------------------------------------------------------------------------
// agg2: one wave per dst node; 4 edges x 16 lanes x float4, unroll 2.
__global__ __launch_bounds__(256) void agg2_kernel(
    const int* __restrict__ offsets, const int* __restrict__ sorted_src,
    const float* __restrict__ H2p, const float* __restrict__ norm_dst,
    const float* __restrict__ b2, float* __restrict__ OUT) {
    int wid = (blockIdx.x * 256 + threadIdx.x) >> 6;
    int lane = threadIdx.x & 63;
    if (wid >= N_NODES) return;
    int start = offsets[wid], end = offsets[wid + 1];
    int quad = lane >> 4;
    int c4 = (lane & 15) * 4;
    bool active = c4 < N_CLASSES;
    float4 acc = make_float4(0.f, 0.f, 0.f, 0.f);
    int base = start;
    int nfull = (end - start) & ~7;
    for (; base < start + nfull; base += 8) {
        int e0 = sorted_src[base + quad];
        int e1 = sorted_src[base + 4 + quad];
        if (active) {
            float4 v0 = *(const float4*)&H2p[(size_t)e0 * 64 + c4];
            float4 v1 = *(const float4*)&H2p[(size_t)e1 * 64 + c4];
            acc.x += v0.x + v1.x;
            acc.y += v0.y + v1.y;
            acc.z += v0.z + v1.z;
            acc.w += v0.w + v1.w;
        }
    }
    int rem = end - base;
    int n4 = rem & ~3;
    for (int t = 0; t < n4; t += 4) {
        int e = sorted_src[base + t + quad];
        if (active) {
            float4 v = *(const float4*)&H2p[(size_t)e * 64 + c4];
            acc.x += v.x; acc.y += v.y; acc.z += v.z; acc.w += v.w;
        }
    }
    base += n4;
    if (quad < end - base && active) {
        int e = sorted_src[base + quad];
        float4 v = *(const float4*)&H2p[(size_t)e * 64 + c4];
        acc.x += v.x; acc.y += v.y; acc.z += v.z; acc.w += v.w;
    }
    acc.x += __shfl_xor(acc.x, 16); acc.x += __shfl_xor(acc.x, 32);
    acc.y += __shfl_xor(acc.y, 16); acc.y += __shfl_xor(acc.y, 32);
    acc.z += __shfl_xor(acc.z, 16); acc.z += __shfl_xor(acc.z, 32);
    acc.w += __shfl_xor(acc.w, 16); acc.w += __shfl_xor(acc.w, 32);
    if (lane < 10) {
        float nd = norm_dst[wid];
        float4 b = *(const float4*)&b2[lane * 4];
        acc.x = acc.x * nd + b.x;
        acc.y = acc.y * nd + b.y;
        acc.z = acc.z * nd + b.z;
        acc.w = acc.w * nd + b.w;
        *(float4*)&OUT[(size_t)wid * N_CLASSES + lane * 4] = acc;
    }
}

// ---------------------------------------------------------------------------
extern "C" void kernel_launch(void* const* d_in, const int* in_sizes, int n_in,
                              void* d_out, int out_size, void* d_ws, size_t ws_size,
                              hipStream_t stream) {
    const float* X   = (const float*)d_in[0];
    const float* W1  = (const float*)d_in[1];
    const float* b1  = (const float*)d_in[2];
    const float* W2  = (const float*)d_in[3];
    const float* b2  = (const float*)d_in[4];
    const int*   src = (const int*)d_in[5];
    const int*   dst = (const int*)d_in[6];
    float* out = (float*)d_out;

    // workspace layout (4B units). regionA (3.2M dwords) time-shared:
    //   phase 1: histD|histS|baseD|baseS|totD|totS      [dead after P3]
    //   phase 2: Hb bf16 50000x128 (1.6M dwords)        [dead after agg1]
    //   phase 3: H2p f32 50000x64 (3.2M dwords)
    float* norm_src   = (float*)d_ws;                     // 50000
    float* norm_dst   = norm_src + N_NODES;               // 50000
    int*   offsets    = (int*)(norm_dst + N_NODES);       // 50016 (incl pad)
    int*   bucket_base = offsets + N_NODES + 16;          // 800
    int*   srcb_base  = bucket_base + 800;                // 800
    unsigned int* edata = (unsigned int*)(srcb_base + 800);       // 1.6M
    unsigned char* srcv = (unsigned char*)(edata + N_EDGES);      // 1.6MB (400K dw)
    int*   sorted_src = (int*)(edata + N_EDGES) + 400000; // 1.6M
    int*   regionA    = sorted_src + N_EDGES;             // 3.2M
    int*   histD      = regionA;
    int*   histS      = regionA + 625600;
    int*   baseD      = regionA + 1251200;
    int*   baseS      = regionA + 1876800;
    int*   totD       = regionA + 2502400;                // 800
    int*   totS       = regionA + 2503200;                // 800
    unsigned short* Hb = (unsigned short*)regionA;
    float* H2p        = (float*)regionA;
    float* H1         = (float*)(regionA + 3200000);      // 1.6M
    unsigned short* W1th = (unsigned short*)(H1 + (size_t)N_NODES * N_HIDDEN);
    unsigned short* W1tl = W1th + IN_FEATS * N_HIDDEN;

    p1_hist<<<NBLK, 256, 0, stream>>>(src, dst, histD, histS);
    p2_local<<<(NBKT + 3) / 4, 256, 0, stream>>>(histD, histS, baseD, baseS, totD, totS);
    p2_small<<<1, 1024, 0, stream>>>(totD, totS, bucket_base, srcb_base, offsets);
    p3_scatter<<<NBLK, 256, 0, stream>>>(src, dst, baseD, baseS, bucket_base, srcb_base,
                                         edata, srcv);
    p4_count<<<NBKT, 256, 0, stream>>>(srcb_base, srcv, norm_src);
    p4_build<<<NBKT, 256, 0, stream>>>(bucket_base, edata, offsets, norm_dst, sorted_src);

    w1cvt_kernel<<<(IN_FEATS * N_HIDDEN + 255) / 256, 256, 0, stream>>>(W1, W1th, W1tl);
    gemm1_kernel<<<(N_NODES + 127) / 128, 256, 0, stream>>>(X, W1th, W1tl, norm_src, Hb);
    agg1_kernel<<<(N_NODES + 3) / 4, 256, 0, stream>>>(offsets, sorted_src, Hb, norm_dst, b1, H1);
    gemm2_kernel<<<(N_NODES + 3) / 4, 256, 0, stream>>>(H1, W2, norm_src, H2p);
    agg2_kernel<<<(N_NODES + 3) / 4, 256, 0, stream>>>(offsets, sorted_src, H2p, norm_dst, b2, out);
}

// Round 7
// 409.121 us; speedup vs baseline: 1.6019x; 1.1827x over previous
//
#include <hip/hip_runtime.h>

#define N_NODES 50000
#define N_EDGES 1600000
#define IN_FEATS 512
#define N_HIDDEN 128
#define N_CLASSES 40
#define NBKT 782      // ceil(50000/64) buckets of 64 nodes
#define NBLK 800      // partition blocks
#define EPB 2000      // edges per partition block (800*2000 = 1.6M exact)
#define NROWPAD 50048 // 391*128, padded row count for gemm2 A-reads

typedef __attribute__((ext_vector_type(8))) short bf16x8;
typedef __attribute__((ext_vector_type(4))) float f32x4;

__device__ __forceinline__ unsigned short f2bf(float f) {
    unsigned u = __float_as_uint(f);
    u = (u + 0x7FFFu + ((u >> 16) & 1u)) >> 16;   // round-to-nearest-even
    return (unsigned short)u;
}
__device__ __forceinline__ float bf2f(unsigned short h) {
    return __uint_as_float(((unsigned)h) << 16);
}

// ---------------------------------------------------------------------------
// P1: per-block LDS histograms by dst-bucket and src-bucket. No global atomics.
__global__ __launch_bounds__(256) void p1_hist(
    const int* __restrict__ src, const int* __restrict__ dst,
    int* __restrict__ histD, int* __restrict__ histS) {
    __shared__ int hd[NBKT], hs[NBKT];
    int t = threadIdx.x, b = blockIdx.x;
    for (int i = t; i < NBKT; i += 256) { hd[i] = 0; hs[i] = 0; }
    __syncthreads();
    int e0 = b * EPB;
    for (int i = t; i < EPB; i += 256) {
        atomicAdd(&hd[dst[e0 + i] >> 6], 1);
        atomicAdd(&hs[src[e0 + i] >> 6], 1);
    }
    __syncthreads();
    for (int i = t; i < NBKT; i += 256) {
        histD[b * NBKT + i] = hd[i];
        histS[b * NBKT + i] = hs[i];
    }
}

// ---------------------------------------------------------------------------
// P2a: one wave per bucket — parallel scan over the 800-block dimension.
__global__ __launch_bounds__(256) void p2_local(
    const int* __restrict__ histD, const int* __restrict__ histS,
    int* __restrict__ baseD, int* __restrict__ baseS,
    int* __restrict__ totD, int* __restrict__ totS) {
    int wv = threadIdx.x >> 6, lane = threadIdx.x & 63;
    int w = blockIdx.x * 4 + wv;
    if (w >= NBKT) return;
    int runD = 0, runS = 0;
#pragma unroll
    for (int c = 0; c < 13; c++) {
        int blk = c * 64 + lane;
        int vD = 0, vS = 0;
        if (blk < NBLK) {
            vD = histD[blk * NBKT + w];
            vS = histS[blk * NBKT + w];
        }
        int iD = vD, iS = vS;
#pragma unroll
        for (int off = 1; off < 64; off <<= 1) {
            int tD = __shfl_up(iD, off);
            int tS = __shfl_up(iS, off);
            if (lane >= off) { iD += tD; iS += tS; }
        }
        if (blk < NBLK) {
            baseD[blk * NBKT + w] = runD + iD - vD;
            baseS[blk * NBKT + w] = runS + iS - vS;
        }
        runD += __shfl(iD, 63);
        runS += __shfl(iS, 63);
    }
    if (lane == 0) { totD[w] = runD; totS[w] = runS; }
}

// P2b: single-block scan over the 782 bucket totals only.
__global__ __launch_bounds__(1024) void p2_small(
    const int* __restrict__ totD, const int* __restrict__ totS,
    int* __restrict__ bucket_base, int* __restrict__ srcb_base,
    int* __restrict__ offsets) {
    __shared__ int part[1024];
    int t = threadIdx.x;
    int v = (t < NBKT) ? totD[t] : 0;
    part[t] = v;
    __syncthreads();
    for (int off = 1; off < 1024; off <<= 1) {
        int x = (t >= off) ? part[t - off] : 0;
        __syncthreads();
        part[t] += x;
        __syncthreads();
    }
    if (t < NBKT) bucket_base[t] = part[t] - v;
    if (t == 0) { bucket_base[NBKT] = N_EDGES; offsets[N_NODES] = N_EDGES; }
    __syncthreads();
    v = (t < NBKT) ? totS[t] : 0;
    part[t] = v;
    __syncthreads();
    for (int off = 1; off < 1024; off <<= 1) {
        int x = (t >= off) ? part[t - off] : 0;
        __syncthreads();
        part[t] += x;
        __syncthreads();
    }
    if (t < NBKT) srcb_base[t] = part[t] - v;
    if (t == 0) srcb_base[NBKT] = N_EDGES;
}

// ---------------------------------------------------------------------------
// P3: scatter edges into bucket-partitioned arrays via LDS cursors.
__global__ __launch_bounds__(256) void p3_scatter(
    const int* __restrict__ src, const int* __restrict__ dst,
    const int* __restrict__ baseD, const int* __restrict__ baseS,
    const int* __restrict__ bucket_base, const int* __restrict__ srcb_base,
    unsigned int* __restrict__ edata, unsigned char* __restrict__ srcv) {
    __shared__ int curD[NBKT], curS[NBKT];
    int t = threadIdx.x, b = blockIdx.x;
    for (int i = t; i < NBKT; i += 256) {
        curD[i] = bucket_base[i] + baseD[b * NBKT + i];
        curS[i] = srcb_base[i] + baseS[b * NBKT + i];
    }
    __syncthreads();
    int e0 = b * EPB;
    for (int i = t; i < EPB; i += 256) {
        int s = src[e0 + i], d = dst[e0 + i];
        int slotD = atomicAdd(&curD[d >> 6], 1);
        edata[slotD] = (unsigned)s | ((unsigned)(d & 63) << 16);
        int slotS = atomicAdd(&curS[s >> 6], 1);
        srcv[slotS] = (unsigned char)(s & 63);
    }
}

// ---------------------------------------------------------------------------
// P4count: exact out-degree per node from src-bucketed bytes -> norm_src.
__global__ __launch_bounds__(256) void p4_count(
    const int* __restrict__ srcb_base, const unsigned char* __restrict__ srcv,
    float* __restrict__ norm_src) {
    __shared__ int cnt[64];
    int t = threadIdx.x, b = blockIdx.x;
    if (t < 64) cnt[t] = 0;
    __syncthreads();
    int s0 = srcb_base[b], s1 = srcb_base[b + 1];
    for (int i = s0 + t; i < s1; i += 256) atomicAdd(&cnt[srcv[i]], 1);
    __syncthreads();
    if (t < 64) {
        int node = b * 64 + t;
        if (node < N_NODES) norm_src[node] = rsqrtf(fmaxf((float)cnt[t], 1.0f));
    }
}

// ---------------------------------------------------------------------------
// P4build: per dst-bucket exact CSR (offsets + sorted_src) + norm_dst.
__global__ __launch_bounds__(256) void p4_build(
    const int* __restrict__ bucket_base, const unsigned int* __restrict__ edata,
    int* __restrict__ offsets, float* __restrict__ norm_dst,
    int* __restrict__ sorted_src) {
    __shared__ int cnt[64], cur[64];
    int t = threadIdx.x, b = blockIdx.x;
    if (t < 64) cnt[t] = 0;
    __syncthreads();
    int s0 = bucket_base[b], s1 = bucket_base[b + 1];
    for (int i = s0 + t; i < s1; i += 256)
        atomicAdd(&cnt[(edata[i] >> 16) & 63], 1);
    __syncthreads();
    if (t == 0) {
        int run = 0;
        for (int i = 0; i < 64; i++) { cur[i] = run; run += cnt[i]; }
    }
    __syncthreads();
    if (t < 64) {
        int node = b * 64 + t;
        if (node < N_NODES) {
            offsets[node] = s0 + cur[t];
            norm_dst[node] = rsqrtf(fmaxf((float)cnt[t], 1.0f));
        }
    }
    __syncthreads();
    for (int i = s0 + t; i < s1; i += 256) {
        unsigned e = edata[i];
        int slot = atomicAdd(&cur[(e >> 16) & 63], 1);
        sorted_src[s0 + slot] = (int)(e & 0xFFFFu);
    }
}

// ---------------------------------------------------------------------------
// pre-convert W1 [512][128] -> transposed bf16 hi/lo [col][k]
__global__ __launch_bounds__(256) void w1cvt_kernel(const float* __restrict__ W1,
                                                    unsigned short* __restrict__ Wth,
                                                    unsigned short* __restrict__ Wtl) {
    int i = blockIdx.x * 256 + threadIdx.x;
    if (i >= IN_FEATS * N_HIDDEN) return;
    int k = i >> 7, c = i & 127;
    float v = W1[i];
    unsigned short h = f2bf(v);
    Wth[c * IN_FEATS + k] = h;
    Wtl[c * IN_FEATS + k] = f2bf(v - bf2f(h));
}

// pre-convert W2 [128][40] -> transposed bf16 hi/lo [48][128], zero-padded
__global__ __launch_bounds__(256) void w2cvt_kernel(const float* __restrict__ W2,
                                                    unsigned short* __restrict__ Wth,
                                                    unsigned short* __restrict__ Wtl) {
    int i = blockIdx.x * 256 + threadIdx.x;   // 48*128 = 6144
    if (i >= 48 * 128) return;
    int n = i >> 7, k = i & 127;
    float v = (n < N_CLASSES) ? W2[k * N_CLASSES + n] : 0.f;
    unsigned short h = f2bf(v);
    Wth[n * 128 + k] = h;
    Wtl[n * 128 + k] = f2bf(v - bf2f(h));
}

// ---------------------------------------------------------------------------
// GEMM1 via bf16 MFMA, split-precision (xh*wh + xh*wl + xl*wh).
// Block tile 128x128, BK=32, 4 waves in 2x2 grid. Output H in bf16.
__global__ __launch_bounds__(256) void gemm1_kernel(
    const float* __restrict__ X, const unsigned short* __restrict__ Wth,
    const unsigned short* __restrict__ Wtl,
    const float* __restrict__ norm_src, unsigned short* __restrict__ Hb) {
    __shared__ __align__(16) unsigned short Xh[128][40];
    __shared__ __align__(16) unsigned short Xl[128][40];
    __shared__ __align__(16) unsigned short Wh[128][40];
    __shared__ __align__(16) unsigned short Wl[128][40];
    const int tid = threadIdx.x;
    const int lane = tid & 63;
    const int wave = tid >> 6;
    const int wr = (wave & 1) * 64;
    const int wc = (wave >> 1) * 64;
    const int row0 = blockIdx.x * 128;
    const int m = lane & 15;
    const int q = lane >> 4;

    f32x4 acc[4][4];
#pragma unroll
    for (int i = 0; i < 4; i++)
#pragma unroll
        for (int j = 0; j < 4; j++) acc[i][j] = (f32x4){0.f, 0.f, 0.f, 0.f};

    for (int k0 = 0; k0 < IN_FEATS; k0 += 32) {
#pragma unroll
        for (int l = 0; l < 4; l++) {
            int s = tid + l * 256;
            int r = s >> 3;
            int kq = (s & 7) * 4;
            float4 v = make_float4(0.f, 0.f, 0.f, 0.f);
            int grow = row0 + r;
            if (grow < N_NODES) v = *(const float4*)&X[(size_t)grow * IN_FEATS + k0 + kq];
            unsigned short h0 = f2bf(v.x), h1 = f2bf(v.y), h2 = f2bf(v.z), h3 = f2bf(v.w);
            unsigned short l0 = f2bf(v.x - bf2f(h0)), l1 = f2bf(v.y - bf2f(h1));
            unsigned short l2 = f2bf(v.z - bf2f(h2)), l3 = f2bf(v.w - bf2f(h3));
            uint2 ph = make_uint2((unsigned)h0 | ((unsigned)h1 << 16),
                                  (unsigned)h2 | ((unsigned)h3 << 16));
            uint2 pl = make_uint2((unsigned)l0 | ((unsigned)l1 << 16),
                                  (unsigned)l2 | ((unsigned)l3 << 16));
            *(uint2*)&Xh[r][kq] = ph;
            *(uint2*)&Xl[r][kq] = pl;
        }
#pragma unroll
        for (int l = 0; l < 2; l++) {
            int s = tid + l * 256;
            int c = s >> 2;
            int kq = (s & 3) * 8;
            *(uint4*)&Wh[c][kq] = *(const uint4*)&Wth[(size_t)c * IN_FEATS + k0 + kq];
            *(uint4*)&Wl[c][kq] = *(const uint4*)&Wtl[(size_t)c * IN_FEATS + k0 + kq];
        }
        __syncthreads();

        bf16x8 ah[4], al[4], bh[4], bl[4];
#pragma unroll
        for (int i = 0; i < 4; i++) {
            ah[i] = *(const bf16x8*)&Xh[wr + i * 16 + m][q * 8];
            al[i] = *(const bf16x8*)&Xl[wr + i * 16 + m][q * 8];
            bh[i] = *(const bf16x8*)&Wh[wc + i * 16 + m][q * 8];
            bl[i] = *(const bf16x8*)&Wl[wc + i * 16 + m][q * 8];
        }
#pragma unroll
        for (int i = 0; i < 4; i++)
#pragma unroll
            for (int j = 0; j < 4; j++) {
                acc[i][j] = __builtin_amdgcn_mfma_f32_16x16x32_bf16(ah[i], bh[j], acc[i][j], 0, 0, 0);
                acc[i][j] = __builtin_amdgcn_mfma_f32_16x16x32_bf16(ah[i], bl[j], acc[i][j], 0, 0, 0);
                acc[i][j] = __builtin_amdgcn_mfma_f32_16x16x32_bf16(al[i], bh[j], acc[i][j], 0, 0, 0);
            }
        __syncthreads();
    }
    // epilogue: C/D layout col=lane&15, row=(lane>>4)*4+reg; store bf16
#pragma unroll
    for (int i = 0; i < 4; i++) {
#pragma unroll
        for (int r = 0; r < 4; r++) {
            int grow = row0 + wr + i * 16 + q * 4 + r;
            if (grow < N_NODES) {
                float sc = norm_src[grow];
#pragma unroll
                for (int j = 0; j < 4; j++)
                    Hb[(size_t)grow * N_HIDDEN + wc + j * 16 + m] = f2bf(acc[i][j][r] * sc);
            }
        }
    }
}

// ---------------------------------------------------------------------------
// agg1: one wave per dst node; 4 edges x 16 lanes x bf16x8 (uint4) per step,
// unroll 2, f32 accum, xor-16/32 butterfly, fused norm+bias+relu.
// Writes H1 = relu(...)*norm_src as bf16 hi/lo (split precision for gemm2 MFMA).
#define ADD8(W)                                               \
    acc0 += __uint_as_float((W).x << 16);                     \
    acc1 += __uint_as_float((W).x & 0xffff0000u);             \
    acc2 += __uint_as_float((W).y << 16);                     \
    acc3 += __uint_as_float((W).y & 0xffff0000u);             \
    acc4 += __uint_as_float((W).z << 16);                     \
    acc5 += __uint_as_float((W).z & 0xffff0000u);             \
    acc6 += __uint_as_float((W).w << 16);                     \
    acc7 += __uint_as_float((W).w & 0xffff0000u);

__global__ __launch_bounds__(256) void agg1_kernel(
    const int* __restrict__ offsets, const int* __restrict__ sorted_src,
    const unsigned short* __restrict__ Hb, const float* __restrict__ norm_dst,
    const float* __restrict__ norm_src, const float* __restrict__ b1,
    unsigned short* __restrict__ H1h, unsigned short* __restrict__ H1l) {
    int wid = (blockIdx.x * 256 + threadIdx.x) >> 6;
    int lane = threadIdx.x & 63;
    if (wid >= N_NODES) return;
    int start = offsets[wid], end = offsets[wid + 1];
    int quad = lane >> 4;
    int c8 = (lane & 15) * 8;
    float acc0 = 0.f, acc1 = 0.f, acc2 = 0.f, acc3 = 0.f;
    float acc4 = 0.f, acc5 = 0.f, acc6 = 0.f, acc7 = 0.f;
    int base = start;
    for (; base + 8 <= end; base += 8) {
        int e0 = sorted_src[base + quad];
        int e1 = sorted_src[base + 4 + quad];
        uint4 w0 = *(const uint4*)&Hb[(size_t)e0 * N_HIDDEN + c8];
        uint4 w1 = *(const uint4*)&Hb[(size_t)e1 * N_HIDDEN + c8];
        ADD8(w0);
        ADD8(w1);
    }
    int rem = end - base;
    if (quad < rem) {
        int e = sorted_src[base + quad];
        uint4 w = *(const uint4*)&Hb[(size_t)e * N_HIDDEN + c8];
        ADD8(w);
    }
    if (quad + 4 < rem) {
        int e = sorted_src[base + 4 + quad];
        uint4 w = *(const uint4*)&Hb[(size_t)e * N_HIDDEN + c8];
        ADD8(w);
    }
    acc0 += __shfl_xor(acc0, 16); acc0 += __shfl_xor(acc0, 32);
    acc1 += __shfl_xor(acc1, 16); acc1 += __shfl_xor(acc1, 32);
    acc2 += __shfl_xor(acc2, 16); acc2 += __shfl_xor(acc2, 32);
    acc3 += __shfl_xor(acc3, 16); acc3 += __shfl_xor(acc3, 32);
    acc4 += __shfl_xor(acc4, 16); acc4 += __shfl_xor(acc4, 32);
    acc5 += __shfl_xor(acc5, 16); acc5 += __shfl_xor(acc5, 32);
    acc6 += __shfl_xor(acc6, 16); acc6 += __shfl_xor(acc6, 32);
    acc7 += __shfl_xor(acc7, 16); acc7 += __shfl_xor(acc7, 32);
    if (quad == 0) {
        float nd = norm_dst[wid];
        float ns = norm_src[wid];
        float4 ba = *(const float4*)&b1[c8];
        float4 bb = *(const float4*)&b1[c8 + 4];
        float o[8];
        o[0] = fmaxf(acc0 * nd + ba.x, 0.f) * ns;
        o[1] = fmaxf(acc1 * nd + ba.y, 0.f) * ns;
        o[2] = fmaxf(acc2 * nd + ba.z, 0.f) * ns;
        o[3] = fmaxf(acc3 * nd + ba.w, 0.f) * ns;
        o[4] = fmaxf(acc4 * nd + bb.x, 0.f) * ns;
        o[5] = fmaxf(acc5 * nd + bb.y, 0.f) * ns;
        o[6] = fmaxf(acc6 * nd + bb.z, 0.f) * ns;
        o[7] = fmaxf(acc7 * nd + bb.w, 0.f) * ns;
        unsigned short hh[8], ll[8];
#pragma unroll
        for (int t = 0; t < 8; t++) {
            hh[t] = f2bf(o[t]);
            ll[t] = f2bf(o[t] - bf2f(hh[t]));
        }
        uint4 ph = make_uint4((unsigned)hh[0] | ((unsigned)hh[1] << 16),
                              (unsigned)hh[2] | ((unsigned)hh[3] << 16),
                              (unsigned)hh[4] | ((unsigned)hh[5] << 16),
                              (unsigned)hh[6] | ((unsigned)hh[7] << 16));
        uint4 pl = make_uint4((unsigned)ll[0] | ((unsigned)ll[1] << 16),
                              (unsigned)ll[2] | ((unsigned)ll[3] << 16),
                              (unsigned)ll[4] | ((unsigned)ll[5] << 16),
                              (unsigned)ll[6] | ((unsigned)ll[7] << 16));
        *(uint4*)&H1h[(size_t)wid * N_HIDDEN + c8] = ph;
        *(uint4*)&H1l[(size_t)wid * N_HIDDEN + c8] = pl;
    }
}

// ---------------------------------------------------------------------------
// GEMM2 via bf16 MFMA: H2p[n][0:40] = H1n @ W2 (norm_src pre-folded into H1).
// 128 rows/block (4 waves x 2 m-tiles), N=48 (3 n-tiles), K=128 (4 chunks).
__global__ __launch_bounds__(256) void gemm2_kernel(
    const unsigned short* __restrict__ H1h, const unsigned short* __restrict__ H1l,
    const unsigned short* __restrict__ W2th, const unsigned short* __restrict__ W2tl,
    float* __restrict__ H2p) {
    __shared__ __align__(16) unsigned short Bh[48][136];
    __shared__ __align__(16) unsigned short Bl[48][136];
    const int tid = threadIdx.x;
    for (int i = tid; i < 48 * 16; i += 256) {      // 16B chunks of the 48x128 tiles
        int n = i >> 4, kq = (i & 15) * 8;
        *(uint4*)&Bh[n][kq] = *(const uint4*)&W2th[n * 128 + kq];
        *(uint4*)&Bl[n][kq] = *(const uint4*)&W2tl[n * 128 + kq];
    }
    __syncthreads();
    const int lane = tid & 63;
    const int wave = tid >> 6;
    const int m = lane & 15;
    const int q = lane >> 4;
    const int row0 = blockIdx.x * 128 + wave * 32;

    f32x4 acc[2][3];
#pragma unroll
    for (int i = 0; i < 2; i++)
#pragma unroll
        for (int j = 0; j < 3; j++) acc[i][j] = (f32x4){0.f, 0.f, 0.f, 0.f};

#pragma unroll
    for (int kc = 0; kc < 4; kc++) {
        bf16x8 bh[3], bl[3];
#pragma unroll
        for (int j = 0; j < 3; j++) {
            bh[j] = *(const bf16x8*)&Bh[j * 16 + m][kc * 32 + q * 8];
            bl[j] = *(const bf16x8*)&Bl[j * 16 + m][kc * 32 + q * 8];
        }
#pragma unroll
        for (int i = 0; i < 2; i++) {
            size_t ro = (size_t)(row0 + i * 16 + m) * N_HIDDEN + kc * 32 + q * 8;
            bf16x8 ah = *(const bf16x8*)&H1h[ro];
            bf16x8 al = *(const bf16x8*)&H1l[ro];
#pragma unroll
            for (int j = 0; j < 3; j++) {
                acc[i][j] = __builtin_amdgcn_mfma_f32_16x16x32_bf16(ah, bh[j], acc[i][j], 0, 0, 0);
                acc[i][j] = __builtin_amdgcn_mfma_f32_16x16x32_bf16(ah, bl[j], acc[i][j], 0, 0, 0);
                acc[i][j] = __builtin_amdgcn_mfma_f32_16x16x32_bf16(al, bh[j], acc[i][j], 0, 0, 0);
            }
        }
    }
    // epilogue: C/D col=lane&15, row=q*4+reg; pitch-64 f32 out, mask col<40
#pragma unroll
    for (int i = 0; i < 2; i++) {
#pragma unroll
        for (int r = 0; r < 4; r++) {
            int row = row0 + i * 16 + q * 4 + r;
            if (row < N_NODES) {
#pragma unroll
                for (int j = 0; j < 3; j++) {
                    int col = j * 16 + m;
                    if (col < N_CLASSES)
                        H2p[(size_t)row * 64 + col] = acc[i][j][r];
                }
            }
        }
    }
}

// ---------------------------------------------------------------------------
// agg2: one wave per dst node; 4 edges x 16 lanes x float4, unroll 2.
__global__ __launch_bounds__(256) void agg2_kernel(
    const int* __restrict__ offsets, const int* __restrict__ sorted_src,
    const float* __restrict__ H2p, const float* __restrict__ norm_dst,
    const float* __restrict__ b2, float* __restrict__ OUT) {
    int wid = (blockIdx.x * 256 + threadIdx.x) >> 6;
    int lane = threadIdx.x & 63;
    if (wid >= N_NODES) return;
    int start = offsets[wid], end = offsets[wid + 1];
    int quad = lane >> 4;
    int c4 = (lane & 15) * 4;
    bool active = c4 < N_CLASSES;
    float4 acc = make_float4(0.f, 0.f, 0.f, 0.f);
    int base = start;
    int nfull = (end - start) & ~7;
    for (; base < start + nfull; base += 8) {
        int e0 = sorted_src[base + quad];
        int e1 = sorted_src[base + 4 + quad];
        if (active) {
            float4 v0 = *(const float4*)&H2p[(size_t)e0 * 64 + c4];
            float4 v1 = *(const float4*)&H2p[(size_t)e1 * 64 + c4];
            acc.x += v0.x + v1.x;
            acc.y += v0.y + v1.y;
            acc.z += v0.z + v1.z;
            acc.w += v0.w + v1.w;
        }
    }
    int rem = end - base;
    int n4 = rem & ~3;
    for (int t = 0; t < n4; t += 4) {
        int e = sorted_src[base + t + quad];
        if (active) {
            float4 v = *(const float4*)&H2p[(size_t)e * 64 + c4];
            acc.x += v.x; acc.y += v.y; acc.z += v.z; acc.w += v.w;
        }
    }
    base += n4;
    if (quad < end - base && active) {
        int e = sorted_src[base + quad];
        float4 v = *(const float4*)&H2p[(size_t)e * 64 + c4];
        acc.x += v.x; acc.y += v.y; acc.z += v.z; acc.w += v.w;
    }
    acc.x += __shfl_xor(acc.x, 16); acc.x += __shfl_xor(acc.x, 32);
    acc.y += __shfl_xor(acc.y, 16); acc.y += __shfl_xor(acc.y, 32);
    acc.z += __shfl_xor(acc.z, 16); acc.z += __shfl_xor(acc.z, 32);
    acc.w += __shfl_xor(acc.w, 16); acc.w += __shfl_xor(acc.w, 32);
    if (lane < 10) {
        float nd = norm_dst[wid];
        float4 b = *(const float4*)&b2[lane * 4];
        acc.x = acc.x * nd + b.x;
        acc.y = acc.y * nd + b.y;
        acc.z = acc.z * nd + b.z;
        acc.w = acc.w * nd + b.w;
        *(float4*)&OUT[(size_t)wid * N_CLASSES + lane * 4] = acc;
    }
}

// ---------------------------------------------------------------------------
extern "C" void kernel_launch(void* const* d_in, const int* in_sizes, int n_in,
                              void* d_out, int out_size, void* d_ws, size_t ws_size,
                              hipStream_t stream) {
    const float* X   = (const float*)d_in[0];
    const float* W1  = (const float*)d_in[1];
    const float* b1  = (const float*)d_in[2];
    const float* W2  = (const float*)d_in[3];
    const float* b2  = (const float*)d_in[4];
    const int*   src = (const int*)d_in[5];
    const int*   dst = (const int*)d_in[6];
    float* out = (float*)d_out;

    // workspace layout (4B units). regionA (3.2M dwords) time-shared:
    //   phase 1: histD|histS|baseD|baseS|totD|totS      [dead after P3]
    //   phase 2: Hb bf16 50000x128 (1.6M dwords)        [dead after agg1]
    //   phase 3: H2p f32 50000x64 (3.2M dwords)
    float* norm_src   = (float*)d_ws;                     // 50000
    float* norm_dst   = norm_src + N_NODES;               // 50000
    int*   offsets    = (int*)(norm_dst + N_NODES);       // 50016 (incl pad)
    int*   bucket_base = offsets + N_NODES + 16;          // 800
    int*   srcb_base  = bucket_base + 800;                // 800
    unsigned int* edata = (unsigned int*)(srcb_base + 800);       // 1.6M
    unsigned char* srcv = (unsigned char*)(edata + N_EDGES);      // 1.6MB (400K dw)
    int*   sorted_src = (int*)(edata + N_EDGES) + 400000; // 1.6M
    int*   regionA    = sorted_src + N_EDGES;             // 3.2M
    int*   histD      = regionA;
    int*   histS      = regionA + 625600;
    int*   baseD      = regionA + 1251200;
    int*   baseS      = regionA + 1876800;
    int*   totD       = regionA + 2502400;                // 800
    int*   totS       = regionA + 2503200;                // 800
    unsigned short* Hb = (unsigned short*)regionA;
    float* H2p        = (float*)regionA;
    unsigned short* H1h = (unsigned short*)(regionA + 3200000);   // 50048x128 bf16
    unsigned short* H1l = H1h + (size_t)NROWPAD * N_HIDDEN;
    unsigned short* W1th = H1l + (size_t)NROWPAD * N_HIDDEN;
    unsigned short* W1tl = W1th + IN_FEATS * N_HIDDEN;
    unsigned short* W2th = W1tl + IN_FEATS * N_HIDDEN;            // 48*128
    unsigned short* W2tl = W2th + 48 * 128;

    p1_hist<<<NBLK, 256, 0, stream>>>(src, dst, histD, histS);
    p2_local<<<(NBKT + 3) / 4, 256, 0, stream>>>(histD, histS, baseD, baseS, totD, totS);
    p2_small<<<1, 1024, 0, stream>>>(totD, totS, bucket_base, srcb_base, offsets);
    p3_scatter<<<NBLK, 256, 0, stream>>>(src, dst, baseD, baseS, bucket_base, srcb_base,
                                         edata, srcv);
    p4_count<<<NBKT, 256, 0, stream>>>(srcb_base, srcv, norm_src);
    p4_build<<<NBKT, 256, 0, stream>>>(bucket_base, edata, offsets, norm_dst, sorted_src);

    w1cvt_kernel<<<(IN_FEATS * N_HIDDEN + 255) / 256, 256, 0, stream>>>(W1, W1th, W1tl);
    w2cvt_kernel<<<(48 * 128 + 255) / 256, 256, 0, stream>>>(W2, W2th, W2tl);
    gemm1_kernel<<<(N_NODES + 127) / 128, 256, 0, stream>>>(X, W1th, W1tl, norm_src, Hb);
    agg1_kernel<<<(N_NODES + 3) / 4, 256, 0, stream>>>(offsets, sorted_src, Hb, norm_dst,
                                                       norm_src, b1, H1h, H1l);
    gemm2_kernel<<<(N_NODES + 127) / 128, 256, 0, stream>>>(H1h, H1l, W2th, W2tl, H2p);
    agg2_kernel<<<(N_NODES + 3) / 4, 256, 0, stream>>>(offsets, sorted_src, H2p, norm_dst, b2, out);
}

// Round 8
// 383.901 us; speedup vs baseline: 1.7071x; 1.0657x over previous
//
#include <hip/hip_runtime.h>
#include <hip/hip_bf16.h>

#define N_NODES 50000
#define N_EDGES 1600000
#define IN_FEATS 512
#define N_HIDDEN 128
#define N_CLASSES 40
#define NBKT 782      // ceil(50000/64) buckets of 64 nodes
#define NBLK 800      // partition blocks
#define EPB 2000      // edges per partition block (800*2000 = 1.6M exact)
#define NROWPAD 50048 // 391*128, padded row count for gemm2 A-reads

typedef __attribute__((ext_vector_type(8))) short bf16x8;
typedef __attribute__((ext_vector_type(4))) float f32x4;

__device__ __forceinline__ unsigned short f2bf(float f) {
    unsigned u = __float_as_uint(f);
    u = (u + 0x7FFFu + ((u >> 16) & 1u)) >> 16;   // round-to-nearest-even
    return (unsigned short)u;
}
__device__ __forceinline__ float bf2f(unsigned short h) {
    return __uint_as_float(((unsigned)h) << 16);
}
// packed f32x2 -> bf16x2 (RTNE), lowers to v_cvt_pk_bf16_f32 on gfx950
__device__ __forceinline__ unsigned pk_bf(float a, float b) {
    __hip_bfloat162 h = __float22bfloat162_rn(make_float2(a, b));
    union { __hip_bfloat162 v; unsigned u; } c;
    c.v = h;
    return c.u;   // low 16 = bf(a), high 16 = bf(b)
}

// ---------------------------------------------------------------------------
// P1: per-block LDS histograms by dst-bucket and src-bucket. No global atomics.
__global__ __launch_bounds__(256) void p1_hist(
    const int* __restrict__ src, const int* __restrict__ dst,
    int* __restrict__ histD, int* __restrict__ histS) {
    __shared__ int hd[NBKT], hs[NBKT];
    int t = threadIdx.x, b = blockIdx.x;
    for (int i = t; i < NBKT; i += 256) { hd[i] = 0; hs[i] = 0; }
    __syncthreads();
    int e0 = b * EPB;
    for (int i = t; i < EPB; i += 256) {
        atomicAdd(&hd[dst[e0 + i] >> 6], 1);
        atomicAdd(&hs[src[e0 + i] >> 6], 1);
    }
    __syncthreads();
    for (int i = t; i < NBKT; i += 256) {
        histD[b * NBKT + i] = hd[i];
        histS[b * NBKT + i] = hs[i];
    }
}

// ---------------------------------------------------------------------------
// P2a: one wave per bucket — parallel scan over the 800-block dimension.
__global__ __launch_bounds__(256) void p2_local(
    const int* __restrict__ histD, const int* __restrict__ histS,
    int* __restrict__ baseD, int* __restrict__ baseS,
    int* __restrict__ totD, int* __restrict__ totS) {
    int wv = threadIdx.x >> 6, lane = threadIdx.x & 63;
    int w = blockIdx.x * 4 + wv;
    if (w >= NBKT) return;
    int runD = 0, runS = 0;
#pragma unroll
    for (int c = 0; c < 13; c++) {
        int blk = c * 64 + lane;
        int vD = 0, vS = 0;
        if (blk < NBLK) {
            vD = histD[blk * NBKT + w];
            vS = histS[blk * NBKT + w];
        }
        int iD = vD, iS = vS;
#pragma unroll
        for (int off = 1; off < 64; off <<= 1) {
            int tD = __shfl_up(iD, off);
            int tS = __shfl_up(iS, off);
            if (lane >= off) { iD += tD; iS += tS; }
        }
        if (blk < NBLK) {
            baseD[blk * NBKT + w] = runD + iD - vD;
            baseS[blk * NBKT + w] = runS + iS - vS;
        }
        runD += __shfl(iD, 63);
        runS += __shfl(iS, 63);
    }
    if (lane == 0) { totD[w] = runD; totS[w] = runS; }
}

// P2b: single-block scan over the 782 bucket totals only.
__global__ __launch_bounds__(1024) void p2_small(
    const int* __restrict__ totD, const int* __restrict__ totS,
    int* __restrict__ bucket_base, int* __restrict__ srcb_base,
    int* __restrict__ offsets) {
    __shared__ int part[1024];
    int t = threadIdx.x;
    int v = (t < NBKT) ? totD[t] : 0;
    part[t] = v;
    __syncthreads();
    for (int off = 1; off < 1024; off <<= 1) {
        int x = (t >= off) ? part[t - off] : 0;
        __syncthreads();
        part[t] += x;
        __syncthreads();
    }
    if (t < NBKT) bucket_base[t] = part[t] - v;
    if (t == 0) { bucket_base[NBKT] = N_EDGES; offsets[N_NODES] = N_EDGES; }
    __syncthreads();
    v = (t < NBKT) ? totS[t] : 0;
    part[t] = v;
    __syncthreads();
    for (int off = 1; off < 1024; off <<= 1) {
        int x = (t >= off) ? part[t - off] : 0;
        __syncthreads();
        part[t] += x;
        __syncthreads();
    }
    if (t < NBKT) srcb_base[t] = part[t] - v;
    if (t == 0) srcb_base[NBKT] = N_EDGES;
}

// ---------------------------------------------------------------------------
// P3: scatter edges into bucket-partitioned arrays via LDS cursors.
__global__ __launch_bounds__(256) void p3_scatter(
    const int* __restrict__ src, const int* __restrict__ dst,
    const int* __restrict__ baseD, const int* __restrict__ baseS,
    const int* __restrict__ bucket_base, const int* __restrict__ srcb_base,
    unsigned int* __restrict__ edata, unsigned char* __restrict__ srcv) {
    __shared__ int curD[NBKT], curS[NBKT];
    int t = threadIdx.x, b = blockIdx.x;
    for (int i = t; i < NBKT; i += 256) {
        curD[i] = bucket_base[i] + baseD[b * NBKT + i];
        curS[i] = srcb_base[i] + baseS[b * NBKT + i];
    }
    __syncthreads();
    int e0 = b * EPB;
    for (int i = t; i < EPB; i += 256) {
        int s = src[e0 + i], d = dst[e0 + i];
        int slotD = atomicAdd(&curD[d >> 6], 1);
        edata[slotD] = (unsigned)s | ((unsigned)(d & 63) << 16);
        int slotS = atomicAdd(&curS[s >> 6], 1);
        srcv[slotS] = (unsigned char)(s & 63);
    }
}

// ---------------------------------------------------------------------------
// P4count: exact out-degree per node from src-bucketed bytes -> norm_src.
__global__ __launch_bounds__(256) void p4_count(
    const int* __restrict__ srcb_base, const unsigned char* __restrict__ srcv,
    float* __restrict__ norm_src) {
    __shared__ int cnt[64];
    int t = threadIdx.x, b = blockIdx.x;
    if (t < 64) cnt[t] = 0;
    __syncthreads();
    int s0 = srcb_base[b], s1 = srcb_base[b + 1];
    for (int i = s0 + t; i < s1; i += 256) atomicAdd(&cnt[srcv[i]], 1);
    __syncthreads();
    if (t < 64) {
        int node = b * 64 + t;
        if (node < N_NODES) norm_src[node] = rsqrtf(fmaxf((float)cnt[t], 1.0f));
    }
}

// ---------------------------------------------------------------------------
// P4build: per dst-bucket exact CSR (offsets + sorted_src) + norm_dst.
__global__ __launch_bounds__(256) void p4_build(
    const int* __restrict__ bucket_base, const unsigned int* __restrict__ edata,
    int* __restrict__ offsets, float* __restrict__ norm_dst,
    int* __restrict__ sorted_src) {
    __shared__ int cnt[64], cur[64];
    int t = threadIdx.x, b = blockIdx.x;
    if (t < 64) cnt[t] = 0;
    __syncthreads();
    int s0 = bucket_base[b], s1 = bucket_base[b + 1];
    for (int i = s0 + t; i < s1; i += 256)
        atomicAdd(&cnt[(edata[i] >> 16) & 63], 1);
    __syncthreads();
    if (t == 0) {
        int run = 0;
        for (int i = 0; i < 64; i++) { cur[i] = run; run += cnt[i]; }
    }
    __syncthreads();
    if (t < 64) {
        int node = b * 64 + t;
        if (node < N_NODES) {
            offsets[node] = s0 + cur[t];
            norm_dst[node] = rsqrtf(fmaxf((float)cnt[t], 1.0f));
        }
    }
    __syncthreads();
    for (int i = s0 + t; i < s1; i += 256) {
        unsigned e = edata[i];
        int slot = atomicAdd(&cur[(e >> 16) & 63], 1);
        sorted_src[s0 + slot] = (int)(e & 0xFFFFu);
    }
}

// ---------------------------------------------------------------------------
// pre-convert W1 [512][128] -> k-chunked bf16 hi/lo: W[kc][col][ki], kc=k/32.
// B-fragment loads in gemm1 become contiguous 1KB/wave global reads.
__global__ __launch_bounds__(256) void w1cvt_kernel(const float* __restrict__ W1,
                                                    unsigned short* __restrict__ Wch,
                                                    unsigned short* __restrict__ Wcl) {
    int i = blockIdx.x * 256 + threadIdx.x;
    if (i >= IN_FEATS * N_HIDDEN) return;
    int k = i >> 7, c = i & 127;
    float v = W1[i];
    unsigned short h = f2bf(v);
    int o = (k >> 5) * 4096 + c * 32 + (k & 31);
    Wch[o] = h;
    Wcl[o] = f2bf(v - bf2f(h));
}

// pre-convert W2 [128][40] -> transposed bf16 hi/lo [48][128], zero-padded
__global__ __launch_bounds__(256) void w2cvt_kernel(const float* __restrict__ W2,
                                                    unsigned short* __restrict__ Wth,
                                                    unsigned short* __restrict__ Wtl) {
    int i = blockIdx.x * 256 + threadIdx.x;   // 48*128 = 6144
    if (i >= 48 * 128) return;
    int n = i >> 7, k = i & 127;
    float v = (n < N_CLASSES) ? W2[k * N_CLASSES + n] : 0.f;
    unsigned short h = f2bf(v);
    Wth[n * 128 + k] = h;
    Wtl[n * 128 + k] = f2bf(v - bf2f(h));
}

// ---------------------------------------------------------------------------
// GEMM1 via bf16 MFMA, split-precision (xh*wh + xh*wl + xl*wh).
// 782 blocks x 64 rows; full N=128 (wave wv covers cols wv*32, 2 n-tiles).
// X staged in LDS (hi/lo, 10KB) with register-prefetch pipeline; W read
// directly from L2-resident k-chunked global layout. Output H bf16.
__global__ __launch_bounds__(256) void gemm1_kernel(
    const float* __restrict__ X, const unsigned short* __restrict__ Wch,
    const unsigned short* __restrict__ Wcl,
    const float* __restrict__ norm_src, unsigned short* __restrict__ Hb) {
    __shared__ __align__(16) unsigned short Xh[64][40];
    __shared__ __align__(16) unsigned short Xl[64][40];
    const int tid = threadIdx.x;
    const int lane = tid & 63;
    const int wv = tid >> 6;
    const int m = lane & 15;
    const int q = lane >> 4;
    const int row0 = blockIdx.x * 64;

    // staging slots: 2 float4 per thread (64 rows x 32 k = 512 float4)
    const int r0 = tid >> 3,          kq0 = (tid & 7) * 4;
    const int r1 = (tid + 256) >> 3,  kq1 = (tid & 7) * 4;
    const bool g0 = (row0 + r0) < N_NODES;
    const bool g1 = (row0 + r1) < N_NODES;
    const float* xp0 = &X[(size_t)(row0 + r0) * IN_FEATS + kq0];
    const float* xp1 = &X[(size_t)(row0 + r1) * IN_FEATS + kq1];

    f32x4 acc[4][2];
#pragma unroll
    for (int i = 0; i < 4; i++)
#pragma unroll
        for (int j = 0; j < 2; j++) acc[i][j] = (f32x4){0.f, 0.f, 0.f, 0.f};

    float4 xa0 = g0 ? *(const float4*)xp0 : make_float4(0.f, 0.f, 0.f, 0.f);
    float4 xa1 = g1 ? *(const float4*)xp1 : make_float4(0.f, 0.f, 0.f, 0.f);

    for (int kc = 0; kc < 16; kc++) {
        // cvt + store staged regs (hi/lo split)
        {
            unsigned h0 = pk_bf(xa0.x, xa0.y), h1 = pk_bf(xa0.z, xa0.w);
            unsigned l0 = pk_bf(xa0.x - __uint_as_float(h0 << 16),
                                xa0.y - __uint_as_float(h0 & 0xffff0000u));
            unsigned l1 = pk_bf(xa0.z - __uint_as_float(h1 << 16),
                                xa0.w - __uint_as_float(h1 & 0xffff0000u));
            *(uint2*)&Xh[r0][kq0] = make_uint2(h0, h1);
            *(uint2*)&Xl[r0][kq0] = make_uint2(l0, l1);
            unsigned h2 = pk_bf(xa1.x, xa1.y), h3 = pk_bf(xa1.z, xa1.w);
            unsigned l2 = pk_bf(xa1.x - __uint_as_float(h2 << 16),
                                xa1.y - __uint_as_float(h2 & 0xffff0000u));
            unsigned l3 = pk_bf(xa1.z - __uint_as_float(h3 << 16),
                                xa1.w - __uint_as_float(h3 & 0xffff0000u));
            *(uint2*)&Xh[r1][kq1] = make_uint2(h2, h3);
            *(uint2*)&Xl[r1][kq1] = make_uint2(l2, l3);
        }
        __syncthreads();
        // prefetch next k-chunk of X (in flight during compute)
        if (kc < 15) {
            xa0 = g0 ? *(const float4*)(xp0 + (kc + 1) * 32) : make_float4(0.f, 0.f, 0.f, 0.f);
            xa1 = g1 ? *(const float4*)(xp1 + (kc + 1) * 32) : make_float4(0.f, 0.f, 0.f, 0.f);
        }
        // B-fragments straight from global (L2-resident, coalesced 16B/lane)
        bf16x8 bh[2], bl[2];
#pragma unroll
        for (int j = 0; j < 2; j++) {
            int o = kc * 4096 + (wv * 32 + j * 16 + m) * 32 + q * 8;
            bh[j] = *(const bf16x8*)&Wch[o];
            bl[j] = *(const bf16x8*)&Wcl[o];
        }
        // A-fragments from LDS
        bf16x8 ah[4], al[4];
#pragma unroll
        for (int i = 0; i < 4; i++) {
            ah[i] = *(const bf16x8*)&Xh[i * 16 + m][q * 8];
            al[i] = *(const bf16x8*)&Xl[i * 16 + m][q * 8];
        }
#pragma unroll
        for (int i = 0; i < 4; i++)
#pragma unroll
            for (int j = 0; j < 2; j++) {
                acc[i][j] = __builtin_amdgcn_mfma_f32_16x16x32_bf16(ah[i], bh[j], acc[i][j], 0, 0, 0);
                acc[i][j] = __builtin_amdgcn_mfma_f32_16x16x32_bf16(ah[i], bl[j], acc[i][j], 0, 0, 0);
                acc[i][j] = __builtin_amdgcn_mfma_f32_16x16x32_bf16(al[i], bh[j], acc[i][j], 0, 0, 0);
            }
        __syncthreads();
    }
    // epilogue: C/D layout col=lane&15, row=(lane>>4)*4+reg; store bf16
#pragma unroll
    for (int i = 0; i < 4; i++) {
#pragma unroll
        for (int r = 0; r < 4; r++) {
            int grow = row0 + i * 16 + q * 4 + r;
            if (grow < N_NODES) {
                float sc = norm_src[grow];
#pragma unroll
                for (int j = 0; j < 2; j++)
                    Hb[(size_t)grow * N_HIDDEN + wv * 32 + j * 16 + m] = f2bf(acc[i][j][r] * sc);
            }
        }
    }
}

// ---------------------------------------------------------------------------
// agg1: one wave per dst node; 4 edges x 16 lanes x bf16x8 (uint4) per step,
// unroll 2, f32 accum, xor-16/32 butterfly, fused norm+bias+relu.
// Writes H1 = relu(...)*norm_src as bf16 hi/lo (split precision for gemm2 MFMA).
#define ADD8(W)                                               \
    acc0 += __uint_as_float((W).x << 16);                     \
    acc1 += __uint_as_float((W).x & 0xffff0000u);             \
    acc2 += __uint_as_float((W).y << 16);                     \
    acc3 += __uint_as_float((W).y & 0xffff0000u);             \
    acc4 += __uint_as_float((W).z << 16);                     \
    acc5 += __uint_as_float((W).z & 0xffff0000u);             \
    acc6 += __uint_as_float((W).w << 16);                     \
    acc7 += __uint_as_float((W).w & 0xffff0000u);

__global__ __launch_bounds__(256) void agg1_kernel(
    const int* __restrict__ offsets, const int* __restrict__ sorted_src,
    const unsigned short* __restrict__ Hb, const float* __restrict__ norm_dst,
    const float* __restrict__ norm_src, const float* __restrict__ b1,
    unsigned short* __restrict__ H1h, unsigned short* __restrict__ H1l) {
    int wid = (blockIdx.x * 256 + threadIdx.x) >> 6;
    int lane = threadIdx.x & 63;
    if (wid >= N_NODES) return;
    int start = offsets[wid], end = offsets[wid + 1];
    int quad = lane >> 4;
    int c8 = (lane & 15) * 8;
    float acc0 = 0.f, acc1 = 0.f, acc2 = 0.f, acc3 = 0.f;
    float acc4 = 0.f, acc5 = 0.f, acc6 = 0.f, acc7 = 0.f;
    int base = start;
    for (; base + 8 <= end; base += 8) {
        int e0 = sorted_src[base + quad];
        int e1 = sorted_src[base + 4 + quad];
        uint4 w0 = *(const uint4*)&Hb[(size_t)e0 * N_HIDDEN + c8];
        uint4 w1 = *(const uint4*)&Hb[(size_t)e1 * N_HIDDEN + c8];
        ADD8(w0);
        ADD8(w1);
    }
    int rem = end - base;
    if (quad < rem) {
        int e = sorted_src[base + quad];
        uint4 w = *(const uint4*)&Hb[(size_t)e * N_HIDDEN + c8];
        ADD8(w);
    }
    if (quad + 4 < rem) {
        int e = sorted_src[base + 4 + quad];
        uint4 w = *(const uint4*)&Hb[(size_t)e * N_HIDDEN + c8];
        ADD8(w);
    }
    acc0 += __shfl_xor(acc0, 16); acc0 += __shfl_xor(acc0, 32);
    acc1 += __shfl_xor(acc1, 16); acc1 += __shfl_xor(acc1, 32);
    acc2 += __shfl_xor(acc2, 16); acc2 += __shfl_xor(acc2, 32);
    acc3 += __shfl_xor(acc3, 16); acc3 += __shfl_xor(acc3, 32);
    acc4 += __shfl_xor(acc4, 16); acc4 += __shfl_xor(acc4, 32);
    acc5 += __shfl_xor(acc5, 16); acc5 += __shfl_xor(acc5, 32);
    acc6 += __shfl_xor(acc6, 16); acc6 += __shfl_xor(acc6, 32);
    acc7 += __shfl_xor(acc7, 16); acc7 += __shfl_xor(acc7, 32);
    if (quad == 0) {
        float nd = norm_dst[wid];
        float ns = norm_src[wid];
        float4 ba = *(const float4*)&b1[c8];
        float4 bb = *(const float4*)&b1[c8 + 4];
        float o[8];
        o[0] = fmaxf(acc0 * nd + ba.x, 0.f) * ns;
        o[1] = fmaxf(acc1 * nd + ba.y, 0.f) * ns;
        o[2] = fmaxf(acc2 * nd + ba.z, 0.f) * ns;
        o[3] = fmaxf(acc3 * nd + ba.w, 0.f) * ns;
        o[4] = fmaxf(acc4 * nd + bb.x, 0.f) * ns;
        o[5] = fmaxf(acc5 * nd + bb.y, 0.f) * ns;
        o[6] = fmaxf(acc6 * nd + bb.z, 0.f) * ns;
        o[7] = fmaxf(acc7 * nd + bb.w, 0.f) * ns;
        unsigned short hh[8], ll[8];
#pragma unroll
        for (int t = 0; t < 8; t++) {
            hh[t] = f2bf(o[t]);
            ll[t] = f2bf(o[t] - bf2f(hh[t]));
        }
        uint4 ph = make_uint4((unsigned)hh[0] | ((unsigned)hh[1] << 16),
                              (unsigned)hh[2] | ((unsigned)hh[3] << 16),
                              (unsigned)hh[4] | ((unsigned)hh[5] << 16),
                              (unsigned)hh[6] | ((unsigned)hh[7] << 16));
        uint4 pl = make_uint4((unsigned)ll[0] | ((unsigned)ll[1] << 16),
                              (unsigned)ll[2] | ((unsigned)ll[3] << 16),
                              (unsigned)ll[4] | ((unsigned)ll[5] << 16),
                              (unsigned)ll[6] | ((unsigned)ll[7] << 16));
        *(uint4*)&H1h[(size_t)wid * N_HIDDEN + c8] = ph;
        *(uint4*)&H1l[(size_t)wid * N_HIDDEN + c8] = pl;
    }
}

// ---------------------------------------------------------------------------
// GEMM2 via bf16 MFMA: H2p[n][0:40] = H1n @ W2 (norm_src pre-folded into H1).
// 128 rows/block (4 waves x 2 m-tiles), N=48 (3 n-tiles), K=128 (4 chunks).
__global__ __launch_bounds__(256) void gemm2_kernel(
    const unsigned short* __restrict__ H1h, const unsigned short* __restrict__ H1l,
    const unsigned short* __restrict__ W2th, const unsigned short* __restrict__ W2tl,
    float* __restrict__ H2p) {
    __shared__ __align__(16) unsigned short Bh[48][136];
    __shared__ __align__(16) unsigned short Bl[48][136];
    const int tid = threadIdx.x;
    for (int i = tid; i < 48 * 16; i += 256) {      // 16B chunks of the 48x128 tiles
        int n = i >> 4, kq = (i & 15) * 8;
        *(uint4*)&Bh[n][kq] = *(const uint4*)&W2th[n * 128 + kq];
        *(uint4*)&Bl[n][kq] = *(const uint4*)&W2tl[n * 128 + kq];
    }
    __syncthreads();
    const int lane = tid & 63;
    const int wave = tid >> 6;
    const int m = lane & 15;
    const int q = lane >> 4;
    const int row0 = blockIdx.x * 128 + wave * 32;

    f32x4 acc[2][3];
#pragma unroll
    for (int i = 0; i < 2; i++)
#pragma unroll
        for (int j = 0; j < 3; j++) acc[i][j] = (f32x4){0.f, 0.f, 0.f, 0.f};

#pragma unroll
    for (int kc = 0; kc < 4; kc++) {
        bf16x8 bh[3], bl[3];
#pragma unroll
        for (int j = 0; j < 3; j++) {
            bh[j] = *(const bf16x8*)&Bh[j * 16 + m][kc * 32 + q * 8];
            bl[j] = *(const bf16x8*)&Bl[j * 16 + m][kc * 32 + q * 8];
        }
#pragma unroll
        for (int i = 0; i < 2; i++) {
            size_t ro = (size_t)(row0 + i * 16 + m) * N_HIDDEN + kc * 32 + q * 8;
            bf16x8 ah = *(const bf16x8*)&H1h[ro];
            bf16x8 al = *(const bf16x8*)&H1l[ro];
#pragma unroll
            for (int j = 0; j < 3; j++) {
                acc[i][j] = __builtin_amdgcn_mfma_f32_16x16x32_bf16(ah, bh[j], acc[i][j], 0, 0, 0);
                acc[i][j] = __builtin_amdgcn_mfma_f32_16x16x32_bf16(ah, bl[j], acc[i][j], 0, 0, 0);
                acc[i][j] = __builtin_amdgcn_mfma_f32_16x16x32_bf16(al, bh[j], acc[i][j], 0, 0, 0);
            }
        }
    }
    // epilogue: C/D col=lane&15, row=q*4+reg; pitch-64 f32 out, mask col<40
#pragma unroll
    for (int i = 0; i < 2; i++) {
#pragma unroll
        for (int r = 0; r < 4; r++) {
            int row = row0 + i * 16 + q * 4 + r;
            if (row < N_NODES) {
#pragma unroll
                for (int j = 0; j < 3; j++) {
                    int col = j * 16 + m;
                    if (col < N_CLASSES)
                        H2p[(size_t)row * 64 + col] = acc[i][j][r];
                }
            }
        }
    }
}

// ---------------------------------------------------------------------------
// agg2: one wave per dst node; 4 edges x 16 lanes x float4, unroll 2.
__global__ __launch_bounds__(256) void agg2_kernel(
    const int* __restrict__ offsets, const int* __restrict__ sorted_src,
    const float* __restrict__ H2p, const float* __restrict__ norm_dst,
    const float* __restrict__ b2, float* __restrict__ OUT) {
    int wid = (blockIdx.x * 256 + threadIdx.x) >> 6;
    int lane = threadIdx.x & 63;
    if (wid >= N_NODES) return;
    int start = offsets[wid], end = offsets[wid + 1];
    int quad = lane >> 4;
    int c4 = (lane & 15) * 4;
    bool active = c4 < N_CLASSES;
    float4 acc = make_float4(0.f, 0.f, 0.f, 0.f);
    int base = start;
    int nfull = (end - start) & ~7;
    for (; base < start + nfull; base += 8) {
        int e0 = sorted_src[base + quad];
        int e1 = sorted_src[base + 4 + quad];
        if (active) {
            float4 v0 = *(const float4*)&H2p[(size_t)e0 * 64 + c4];
            float4 v1 = *(const float4*)&H2p[(size_t)e1 * 64 + c4];
            acc.x += v0.x + v1.x;
            acc.y += v0.y + v1.y;
            acc.z += v0.z + v1.z;
            acc.w += v0.w + v1.w;
        }
    }
    int rem = end - base;
    int n4 = rem & ~3;
    for (int t = 0; t < n4; t += 4) {
        int e = sorted_src[base + t + quad];
        if (active) {
            float4 v = *(const float4*)&H2p[(size_t)e * 64 + c4];
            acc.x += v.x; acc.y += v.y; acc.z += v.z; acc.w += v.w;
        }
    }
    base += n4;
    if (quad < end - base && active) {
        int e = sorted_src[base + quad];
        float4 v = *(const float4*)&H2p[(size_t)e * 64 + c4];
        acc.x += v.x; acc.y += v.y; acc.z += v.z; acc.w += v.w;
    }
    acc.x += __shfl_xor(acc.x, 16); acc.x += __shfl_xor(acc.x, 32);
    acc.y += __shfl_xor(acc.y, 16); acc.y += __shfl_xor(acc.y, 32);
    acc.z += __shfl_xor(acc.z, 16); acc.z += __shfl_xor(acc.z, 32);
    acc.w += __shfl_xor(acc.w, 16); acc.w += __shfl_xor(acc.w, 32);
    if (lane < 10) {
        float nd = norm_dst[wid];
        float4 b = *(const float4*)&b2[lane * 4];
        acc.x = acc.x * nd + b.x;
        acc.y = acc.y * nd + b.y;
        acc.z = acc.z * nd + b.z;
        acc.w = acc.w * nd + b.w;
        *(float4*)&OUT[(size_t)wid * N_CLASSES + lane * 4] = acc;
    }
}

// ---------------------------------------------------------------------------
extern "C" void kernel_launch(void* const* d_in, const int* in_sizes, int n_in,
                              void* d_out, int out_size, void* d_ws, size_t ws_size,
                              hipStream_t stream) {
    const float* X   = (const float*)d_in[0];
    const float* W1  = (const float*)d_in[1];
    const float* b1  = (const float*)d_in[2];
    const float* W2  = (const float*)d_in[3];
    const float* b2  = (const float*)d_in[4];
    const int*   src = (const int*)d_in[5];
    const int*   dst = (const int*)d_in[6];
    float* out = (float*)d_out;

    // workspace layout (4B units). regionA (3.2M dwords) time-shared:
    //   phase 1: histD|histS|baseD|baseS|totD|totS      [dead after P3]
    //   phase 2: Hb bf16 50000x128 (1.6M dwords)        [dead after agg1]
    //   phase 3: H2p f32 50000x64 (3.2M dwords)
    float* norm_src   = (float*)d_ws;                     // 50000
    float* norm_dst   = norm_src + N_NODES;               // 50000
    int*   offsets    = (int*)(norm_dst + N_NODES);       // 50016 (incl pad)
    int*   bucket_base = offsets + N_NODES + 16;          // 800
    int*   srcb_base  = bucket_base + 800;                // 800
    unsigned int* edata = (unsigned int*)(srcb_base + 800);       // 1.6M
    unsigned char* srcv = (unsigned char*)(edata + N_EDGES);      // 1.6MB (400K dw)
    int*   sorted_src = (int*)(edata + N_EDGES) + 400000; // 1.6M
    int*   regionA    = sorted_src + N_EDGES;             // 3.2M
    int*   histD      = regionA;
    int*   histS      = regionA + 625600;
    int*   baseD      = regionA + 1251200;
    int*   baseS      = regionA + 1876800;
    int*   totD       = regionA + 2502400;                // 800
    int*   totS       = regionA + 2503200;                // 800
    unsigned short* Hb = (unsigned short*)regionA;
    float* H2p        = (float*)regionA;
    unsigned short* H1h = (unsigned short*)(regionA + 3200000);   // 50048x128 bf16
    unsigned short* H1l = H1h + (size_t)NROWPAD * N_HIDDEN;
    unsigned short* W1ch = H1l + (size_t)NROWPAD * N_HIDDEN;      // k-chunked 512*128
    unsigned short* W1cl = W1ch + IN_FEATS * N_HIDDEN;
    unsigned short* W2th = W1cl + IN_FEATS * N_HIDDEN;            // 48*128
    unsigned short* W2tl = W2th + 48 * 128;

    p1_hist<<<NBLK, 256, 0, stream>>>(src, dst, histD, histS);
    p2_local<<<(NBKT + 3) / 4, 256, 0, stream>>>(histD, histS, baseD, baseS, totD, totS);
    p2_small<<<1, 1024, 0, stream>>>(totD, totS, bucket_base, srcb_base, offsets);
    p3_scatter<<<NBLK, 256, 0, stream>>>(src, dst, baseD, baseS, bucket_base, srcb_base,
                                         edata, srcv);
    p4_count<<<NBKT, 256, 0, stream>>>(srcb_base, srcv, norm_src);
    p4_build<<<NBKT, 256, 0, stream>>>(bucket_base, edata, offsets, norm_dst, sorted_src);

    w1cvt_kernel<<<(IN_FEATS * N_HIDDEN + 255) / 256, 256, 0, stream>>>(W1, W1ch, W1cl);
    w2cvt_kernel<<<(48 * 128 + 255) / 256, 256, 0, stream>>>(W2, W2th, W2tl);
    gemm1_kernel<<<NBKT, 256, 0, stream>>>(X, W1ch, W1cl, norm_src, Hb);
    agg1_kernel<<<(N_NODES + 3) / 4, 256, 0, stream>>>(offsets, sorted_src, Hb, norm_dst,
                                                       norm_src, b1, H1h, H1l);
    gemm2_kernel<<<(N_NODES + 127) / 128, 256, 0, stream>>>(H1h, H1l, W2th, W2tl, H2p);
    agg2_kernel<<<(N_NODES + 3) / 4, 256, 0, stream>>>(offsets, sorted_src, H2p, norm_dst, b2, out);
}

// Round 9
// 371.458 us; speedup vs baseline: 1.7643x; 1.0335x over previous
//
#include <hip/hip_runtime.h>
#include <hip/hip_bf16.h>

#define N_NODES 50000
#define N_EDGES 1600000
#define IN_FEATS 512
#define N_HIDDEN 128
#define N_CLASSES 40
#define NBKT 782      // ceil(50000/64) buckets of 64 nodes
#define NBLK 800      // partition blocks
#define EPB 2000      // edges per partition block (800*2000 = 1.6M exact)
#define NROWPAD 50048 // 391*128, padded row count for gemm2 A-reads

typedef __attribute__((ext_vector_type(8))) short bf16x8;
typedef __attribute__((ext_vector_type(4))) float f32x4;

__device__ __forceinline__ unsigned short f2bf(float f) {
    unsigned u = __float_as_uint(f);
    u = (u + 0x7FFFu + ((u >> 16) & 1u)) >> 16;   // round-to-nearest-even
    return (unsigned short)u;
}
__device__ __forceinline__ float bf2f(unsigned short h) {
    return __uint_as_float(((unsigned)h) << 16);
}
// packed f32x2 -> bf16x2 (RTNE), lowers to v_cvt_pk_bf16_f32 on gfx950
__device__ __forceinline__ unsigned pk_bf(float a, float b) {
    __hip_bfloat162 h = __float22bfloat162_rn(make_float2(a, b));
    union { __hip_bfloat162 v; unsigned u; } c;
    c.v = h;
    return c.u;   // low 16 = bf(a), high 16 = bf(b)
}

// ---------------------------------------------------------------------------
// setup: W1 -> k-chunked bf16 hi/lo [kc][col][ki]; W2 -> transposed [48][128]
__global__ __launch_bounds__(256) void setup_cvt(
    const float* __restrict__ W1, const float* __restrict__ W2,
    unsigned short* __restrict__ W1ch, unsigned short* __restrict__ W1cl,
    unsigned short* __restrict__ W2th, unsigned short* __restrict__ W2tl) {
    int i = blockIdx.x * 256 + threadIdx.x;
    if (i < IN_FEATS * N_HIDDEN) {
        int k = i >> 7, c = i & 127;
        float v = W1[i];
        unsigned short h = f2bf(v);
        int o = (k >> 5) * 4096 + c * 32 + (k & 31);
        W1ch[o] = h;
        W1cl[o] = f2bf(v - bf2f(h));
    } else {
        int j = i - IN_FEATS * N_HIDDEN;    // 0..6143 (grid sized exactly)
        int n = j >> 7, k = j & 127;
        float v = (n < N_CLASSES) ? W2[k * N_CLASSES + n] : 0.f;
        unsigned short h = f2bf(v);
        W2th[n * 128 + k] = h;
        W2tl[n * 128 + k] = f2bf(v - bf2f(h));
    }
}

// ---------------------------------------------------------------------------
// megaA: blocks [0,NBLK) = p1_hist; blocks [NBLK,NBLK+NBKT) = gemm1 tiles.
// gemm1 is norm-free (norm_src applied per-edge in agg1), so it has no
// dependency on graph preprocessing and overlaps with p1's memory work.
__global__ __launch_bounds__(256) void megaA(
    const int* __restrict__ src, const int* __restrict__ dst,
    int* __restrict__ histD, int* __restrict__ histS,
    const float* __restrict__ X, const unsigned short* __restrict__ Wch,
    const unsigned short* __restrict__ Wcl, unsigned short* __restrict__ Hb) {
    __shared__ int hd[NBKT], hs[NBKT];
    __shared__ __align__(16) unsigned short Xh[64][40];
    __shared__ __align__(16) unsigned short Xl[64][40];
    const int tid = threadIdx.x;

    if (blockIdx.x < NBLK) {
        // ---- p1_hist ----
        int b = blockIdx.x;
        for (int i = tid; i < NBKT; i += 256) { hd[i] = 0; hs[i] = 0; }
        __syncthreads();
        int e0 = b * EPB;
        for (int i = tid; i < EPB; i += 256) {
            atomicAdd(&hd[dst[e0 + i] >> 6], 1);
            atomicAdd(&hs[src[e0 + i] >> 6], 1);
        }
        __syncthreads();
        for (int i = tid; i < NBKT; i += 256) {
            histD[b * NBKT + i] = hd[i];
            histS[b * NBKT + i] = hs[i];
        }
        return;
    }
    // ---- gemm1: 64 rows, split-precision bf16 MFMA, unscaled output ----
    const int lane = tid & 63;
    const int wv = tid >> 6;
    const int m = lane & 15;
    const int q = lane >> 4;
    const int row0 = (blockIdx.x - NBLK) * 64;

    const int r0 = tid >> 3,          kq0 = (tid & 7) * 4;
    const int r1 = (tid + 256) >> 3,  kq1 = (tid & 7) * 4;
    const bool g0 = (row0 + r0) < N_NODES;
    const bool g1 = (row0 + r1) < N_NODES;
    const float* xp0 = &X[(size_t)(row0 + r0) * IN_FEATS + kq0];
    const float* xp1 = &X[(size_t)(row0 + r1) * IN_FEATS + kq1];

    f32x4 acc[4][2];
#pragma unroll
    for (int i = 0; i < 4; i++)
#pragma unroll
        for (int j = 0; j < 2; j++) acc[i][j] = (f32x4){0.f, 0.f, 0.f, 0.f};

    float4 xa0 = g0 ? *(const float4*)xp0 : make_float4(0.f, 0.f, 0.f, 0.f);
    float4 xa1 = g1 ? *(const float4*)xp1 : make_float4(0.f, 0.f, 0.f, 0.f);

    for (int kc = 0; kc < 16; kc++) {
        {
            unsigned h0 = pk_bf(xa0.x, xa0.y), h1 = pk_bf(xa0.z, xa0.w);
            unsigned l0 = pk_bf(xa0.x - __uint_as_float(h0 << 16),
                                xa0.y - __uint_as_float(h0 & 0xffff0000u));
            unsigned l1 = pk_bf(xa0.z - __uint_as_float(h1 << 16),
                                xa0.w - __uint_as_float(h1 & 0xffff0000u));
            *(uint2*)&Xh[r0][kq0] = make_uint2(h0, h1);
            *(uint2*)&Xl[r0][kq0] = make_uint2(l0, l1);
            unsigned h2 = pk_bf(xa1.x, xa1.y), h3 = pk_bf(xa1.z, xa1.w);
            unsigned l2 = pk_bf(xa1.x - __uint_as_float(h2 << 16),
                                xa1.y - __uint_as_float(h2 & 0xffff0000u));
            unsigned l3 = pk_bf(xa1.z - __uint_as_float(h3 << 16),
                                xa1.w - __uint_as_float(h3 & 0xffff0000u));
            *(uint2*)&Xh[r1][kq1] = make_uint2(h2, h3);
            *(uint2*)&Xl[r1][kq1] = make_uint2(l2, l3);
        }
        __syncthreads();
        if (kc < 15) {
            xa0 = g0 ? *(const float4*)(xp0 + (kc + 1) * 32) : make_float4(0.f, 0.f, 0.f, 0.f);
            xa1 = g1 ? *(const float4*)(xp1 + (kc + 1) * 32) : make_float4(0.f, 0.f, 0.f, 0.f);
        }
        bf16x8 bh[2], bl[2];
#pragma unroll
        for (int j = 0; j < 2; j++) {
            int o = kc * 4096 + (wv * 32 + j * 16 + m) * 32 + q * 8;
            bh[j] = *(const bf16x8*)&Wch[o];
            bl[j] = *(const bf16x8*)&Wcl[o];
        }
        bf16x8 ah[4], al[4];
#pragma unroll
        for (int i = 0; i < 4; i++) {
            ah[i] = *(const bf16x8*)&Xh[i * 16 + m][q * 8];
            al[i] = *(const bf16x8*)&Xl[i * 16 + m][q * 8];
        }
#pragma unroll
        for (int i = 0; i < 4; i++)
#pragma unroll
            for (int j = 0; j < 2; j++) {
                acc[i][j] = __builtin_amdgcn_mfma_f32_16x16x32_bf16(ah[i], bh[j], acc[i][j], 0, 0, 0);
                acc[i][j] = __builtin_amdgcn_mfma_f32_16x16x32_bf16(ah[i], bl[j], acc[i][j], 0, 0, 0);
                acc[i][j] = __builtin_amdgcn_mfma_f32_16x16x32_bf16(al[i], bh[j], acc[i][j], 0, 0, 0);
            }
        __syncthreads();
    }
#pragma unroll
    for (int i = 0; i < 4; i++) {
#pragma unroll
        for (int r = 0; r < 4; r++) {
            int grow = row0 + i * 16 + q * 4 + r;
            if (grow < N_NODES) {
#pragma unroll
                for (int j = 0; j < 2; j++)
                    Hb[(size_t)grow * N_HIDDEN + wv * 32 + j * 16 + m] = f2bf(acc[i][j][r]);
            }
        }
    }
}

// ---------------------------------------------------------------------------
// P2a: one wave per bucket — parallel scan over the 800-block dimension.
__global__ __launch_bounds__(256) void p2_local(
    const int* __restrict__ histD, const int* __restrict__ histS,
    int* __restrict__ baseD, int* __restrict__ baseS,
    int* __restrict__ totD, int* __restrict__ totS) {
    int wv = threadIdx.x >> 6, lane = threadIdx.x & 63;
    int w = blockIdx.x * 4 + wv;
    if (w >= NBKT) return;
    int runD = 0, runS = 0;
#pragma unroll
    for (int c = 0; c < 13; c++) {
        int blk = c * 64 + lane;
        int vD = 0, vS = 0;
        if (blk < NBLK) {
            vD = histD[blk * NBKT + w];
            vS = histS[blk * NBKT + w];
        }
        int iD = vD, iS = vS;
#pragma unroll
        for (int off = 1; off < 64; off <<= 1) {
            int tD = __shfl_up(iD, off);
            int tS = __shfl_up(iS, off);
            if (lane >= off) { iD += tD; iS += tS; }
        }
        if (blk < NBLK) {
            baseD[blk * NBKT + w] = runD + iD - vD;
            baseS[blk * NBKT + w] = runS + iS - vS;
        }
        runD += __shfl(iD, 63);
        runS += __shfl(iS, 63);
    }
    if (lane == 0) { totD[w] = runD; totS[w] = runS; }
}

// P2b: single-block scan over the 782 bucket totals only.
__global__ __launch_bounds__(1024) void p2_small(
    const int* __restrict__ totD, const int* __restrict__ totS,
    int* __restrict__ bucket_base, int* __restrict__ srcb_base,
    int* __restrict__ offsets) {
    __shared__ int part[1024];
    int t = threadIdx.x;
    int v = (t < NBKT) ? totD[t] : 0;
    part[t] = v;
    __syncthreads();
    for (int off = 1; off < 1024; off <<= 1) {
        int x = (t >= off) ? part[t - off] : 0;
        __syncthreads();
        part[t] += x;
        __syncthreads();
    }
    if (t < NBKT) bucket_base[t] = part[t] - v;
    if (t == 0) { bucket_base[NBKT] = N_EDGES; offsets[N_NODES] = N_EDGES; }
    __syncthreads();
    v = (t < NBKT) ? totS[t] : 0;
    part[t] = v;
    __syncthreads();
    for (int off = 1; off < 1024; off <<= 1) {
        int x = (t >= off) ? part[t - off] : 0;
        __syncthreads();
        part[t] += x;
        __syncthreads();
    }
    if (t < NBKT) srcb_base[t] = part[t] - v;
    if (t == 0) srcb_base[NBKT] = N_EDGES;
}

// ---------------------------------------------------------------------------
// P3: scatter edges into bucket-partitioned arrays via LDS cursors.
__global__ __launch_bounds__(256) void p3_scatter(
    const int* __restrict__ src, const int* __restrict__ dst,
    const int* __restrict__ baseD, const int* __restrict__ baseS,
    const int* __restrict__ bucket_base, const int* __restrict__ srcb_base,
    unsigned int* __restrict__ edata, unsigned char* __restrict__ srcv) {
    __shared__ int curD[NBKT], curS[NBKT];
    int t = threadIdx.x, b = blockIdx.x;
    for (int i = t; i < NBKT; i += 256) {
        curD[i] = bucket_base[i] + baseD[b * NBKT + i];
        curS[i] = srcb_base[i] + baseS[b * NBKT + i];
    }
    __syncthreads();
    int e0 = b * EPB;
    for (int i = t; i < EPB; i += 256) {
        int s = src[e0 + i], d = dst[e0 + i];
        int slotD = atomicAdd(&curD[d >> 6], 1);
        edata[slotD] = (unsigned)s | ((unsigned)(d & 63) << 16);
        int slotS = atomicAdd(&curS[s >> 6], 1);
        srcv[slotS] = (unsigned char)(s & 63);
    }
}

// ---------------------------------------------------------------------------
// P4 fused: src-side count -> norm_src; dst-side count+scatter -> offsets,
// norm_dst, sorted_src. One block per bucket.
__global__ __launch_bounds__(256) void p4_fused(
    const int* __restrict__ srcb_base, const unsigned char* __restrict__ srcv,
    const int* __restrict__ bucket_base, const unsigned int* __restrict__ edata,
    int* __restrict__ offsets, float* __restrict__ norm_src,
    float* __restrict__ norm_dst, int* __restrict__ sorted_src) {
    __shared__ int cntS[64], cntD[64], cur[64];
    int t = threadIdx.x, b = blockIdx.x;
    if (t < 64) { cntS[t] = 0; cntD[t] = 0; }
    __syncthreads();
    int s0 = srcb_base[b], s1 = srcb_base[b + 1];
    for (int i = s0 + t; i < s1; i += 256) atomicAdd(&cntS[srcv[i]], 1);
    int d0 = bucket_base[b], d1 = bucket_base[b + 1];
    for (int i = d0 + t; i < d1; i += 256)
        atomicAdd(&cntD[(edata[i] >> 16) & 63], 1);
    __syncthreads();
    if (t == 0) {
        int run = 0;
        for (int i = 0; i < 64; i++) { cur[i] = run; run += cntD[i]; }
    }
    __syncthreads();
    if (t < 64) {
        int node = b * 64 + t;
        if (node < N_NODES) {
            norm_src[node] = rsqrtf(fmaxf((float)cntS[t], 1.0f));
            offsets[node] = d0 + cur[t];
            norm_dst[node] = rsqrtf(fmaxf((float)cntD[t], 1.0f));
        }
    }
    __syncthreads();
    for (int i = d0 + t; i < d1; i += 256) {
        unsigned e = edata[i];
        int slot = atomicAdd(&cur[(e >> 16) & 63], 1);
        sorted_src[d0 + slot] = (int)(e & 0xFFFFu);
    }
}

// ---------------------------------------------------------------------------
// agg1: one wave per dst node; per-edge norm_src fma (Hb is unscaled),
// 16 edges in flight (4 b128/lane), xor-16/32 butterfly, fused
// norm_dst+bias+relu, H1 out bf16 hi/lo with norm_src[wid] folded (for gemm2).
#define FMA8(W, NS)                                                   \
    acc0 = fmaf(__uint_as_float((W).x << 16), NS, acc0);              \
    acc1 = fmaf(__uint_as_float((W).x & 0xffff0000u), NS, acc1);      \
    acc2 = fmaf(__uint_as_float((W).y << 16), NS, acc2);              \
    acc3 = fmaf(__uint_as_float((W).y & 0xffff0000u), NS, acc3);      \
    acc4 = fmaf(__uint_as_float((W).z << 16), NS, acc4);              \
    acc5 = fmaf(__uint_as_float((W).z & 0xffff0000u), NS, acc5);      \
    acc6 = fmaf(__uint_as_float((W).w << 16), NS, acc6);              \
    acc7 = fmaf(__uint_as_float((W).w & 0xffff0000u), NS, acc7);

__global__ __launch_bounds__(256) void agg1_kernel(
    const int* __restrict__ offsets, const int* __restrict__ sorted_src,
    const unsigned short* __restrict__ Hb, const float* __restrict__ norm_dst,
    const float* __restrict__ norm_src, const float* __restrict__ b1,
    unsigned short* __restrict__ H1h, unsigned short* __restrict__ H1l) {
    int wid = (blockIdx.x * 256 + threadIdx.x) >> 6;
    int lane = threadIdx.x & 63;
    if (wid >= N_NODES) return;
    int start = offsets[wid], end = offsets[wid + 1];
    int quad = lane >> 4;
    int c8 = (lane & 15) * 8;
    float acc0 = 0.f, acc1 = 0.f, acc2 = 0.f, acc3 = 0.f;
    float acc4 = 0.f, acc5 = 0.f, acc6 = 0.f, acc7 = 0.f;
    int base = start;
    for (; base + 16 <= end; base += 16) {
        int e0 = sorted_src[base + quad];
        int e1 = sorted_src[base + 4 + quad];
        int e2 = sorted_src[base + 8 + quad];
        int e3 = sorted_src[base + 12 + quad];
        float n0 = norm_src[e0], n1 = norm_src[e1];
        float n2 = norm_src[e2], n3 = norm_src[e3];
        uint4 w0 = *(const uint4*)&Hb[(size_t)e0 * N_HIDDEN + c8];
        uint4 w1 = *(const uint4*)&Hb[(size_t)e1 * N_HIDDEN + c8];
        uint4 w2 = *(const uint4*)&Hb[(size_t)e2 * N_HIDDEN + c8];
        uint4 w3 = *(const uint4*)&Hb[(size_t)e3 * N_HIDDEN + c8];
        FMA8(w0, n0);
        FMA8(w1, n1);
        FMA8(w2, n2);
        FMA8(w3, n3);
    }
    for (; base + 4 <= end; base += 4) {
        int e = sorted_src[base + quad];
        float n = norm_src[e];
        uint4 w = *(const uint4*)&Hb[(size_t)e * N_HIDDEN + c8];
        FMA8(w, n);
    }
    int rem = end - base;
    if (quad < rem) {
        int e = sorted_src[base + quad];
        float n = norm_src[e];
        uint4 w = *(const uint4*)&Hb[(size_t)e * N_HIDDEN + c8];
        FMA8(w, n);
    }
    acc0 += __shfl_xor(acc0, 16); acc0 += __shfl_xor(acc0, 32);
    acc1 += __shfl_xor(acc1, 16); acc1 += __shfl_xor(acc1, 32);
    acc2 += __shfl_xor(acc2, 16); acc2 += __shfl_xor(acc2, 32);
    acc3 += __shfl_xor(acc3, 16); acc3 += __shfl_xor(acc3, 32);
    acc4 += __shfl_xor(acc4, 16); acc4 += __shfl_xor(acc4, 32);
    acc5 += __shfl_xor(acc5, 16); acc5 += __shfl_xor(acc5, 32);
    acc6 += __shfl_xor(acc6, 16); acc6 += __shfl_xor(acc6, 32);
    acc7 += __shfl_xor(acc7, 16); acc7 += __shfl_xor(acc7, 32);
    if (quad == 0) {
        float nd = norm_dst[wid];
        float ns = norm_src[wid];
        float4 ba = *(const float4*)&b1[c8];
        float4 bb = *(const float4*)&b1[c8 + 4];
        float o[8];
        o[0] = fmaxf(acc0 * nd + ba.x, 0.f) * ns;
        o[1] = fmaxf(acc1 * nd + ba.y, 0.f) * ns;
        o[2] = fmaxf(acc2 * nd + ba.z, 0.f) * ns;
        o[3] = fmaxf(acc3 * nd + ba.w, 0.f) * ns;
        o[4] = fmaxf(acc4 * nd + bb.x, 0.f) * ns;
        o[5] = fmaxf(acc5 * nd + bb.y, 0.f) * ns;
        o[6] = fmaxf(acc6 * nd + bb.z, 0.f) * ns;
        o[7] = fmaxf(acc7 * nd + bb.w, 0.f) * ns;
        unsigned short hh[8], ll[8];
#pragma unroll
        for (int t = 0; t < 8; t++) {
            hh[t] = f2bf(o[t]);
            ll[t] = f2bf(o[t] - bf2f(hh[t]));
        }
        uint4 ph = make_uint4((unsigned)hh[0] | ((unsigned)hh[1] << 16),
                              (unsigned)hh[2] | ((unsigned)hh[3] << 16),
                              (unsigned)hh[4] | ((unsigned)hh[5] << 16),
                              (unsigned)hh[6] | ((unsigned)hh[7] << 16));
        uint4 pl = make_uint4((unsigned)ll[0] | ((unsigned)ll[1] << 16),
                              (unsigned)ll[2] | ((unsigned)ll[3] << 16),
                              (unsigned)ll[4] | ((unsigned)ll[5] << 16),
                              (unsigned)ll[6] | ((unsigned)ll[7] << 16));
        *(uint4*)&H1h[(size_t)wid * N_HIDDEN + c8] = ph;
        *(uint4*)&H1l[(size_t)wid * N_HIDDEN + c8] = pl;
    }
}

// ---------------------------------------------------------------------------
// GEMM2 via bf16 MFMA: H2p[n][0:40] = H1n @ W2 (norm_src pre-folded into H1).
__global__ __launch_bounds__(256) void gemm2_kernel(
    const unsigned short* __restrict__ H1h, const unsigned short* __restrict__ H1l,
    const unsigned short* __restrict__ W2th, const unsigned short* __restrict__ W2tl,
    float* __restrict__ H2p) {
    __shared__ __align__(16) unsigned short Bh[48][136];
    __shared__ __align__(16) unsigned short Bl[48][136];
    const int tid = threadIdx.x;
    for (int i = tid; i < 48 * 16; i += 256) {
        int n = i >> 4, kq = (i & 15) * 8;
        *(uint4*)&Bh[n][kq] = *(const uint4*)&W2th[n * 128 + kq];
        *(uint4*)&Bl[n][kq] = *(const uint4*)&W2tl[n * 128 + kq];
    }
    __syncthreads();
    const int lane = tid & 63;
    const int wave = tid >> 6;
    const int m = lane & 15;
    const int q = lane >> 4;
    const int row0 = blockIdx.x * 128 + wave * 32;

    f32x4 acc[2][3];
#pragma unroll
    for (int i = 0; i < 2; i++)
#pragma unroll
        for (int j = 0; j < 3; j++) acc[i][j] = (f32x4){0.f, 0.f, 0.f, 0.f};

#pragma unroll
    for (int kc = 0; kc < 4; kc++) {
        bf16x8 bh[3], bl[3];
#pragma unroll
        for (int j = 0; j < 3; j++) {
            bh[j] = *(const bf16x8*)&Bh[j * 16 + m][kc * 32 + q * 8];
            bl[j] = *(const bf16x8*)&Bl[j * 16 + m][kc * 32 + q * 8];
        }
#pragma unroll
        for (int i = 0; i < 2; i++) {
            size_t ro = (size_t)(row0 + i * 16 + m) * N_HIDDEN + kc * 32 + q * 8;
            bf16x8 ah = *(const bf16x8*)&H1h[ro];
            bf16x8 al = *(const bf16x8*)&H1l[ro];
#pragma unroll
            for (int j = 0; j < 3; j++) {
                acc[i][j] = __builtin_amdgcn_mfma_f32_16x16x32_bf16(ah, bh[j], acc[i][j], 0, 0, 0);
                acc[i][j] = __builtin_amdgcn_mfma_f32_16x16x32_bf16(ah, bl[j], acc[i][j], 0, 0, 0);
                acc[i][j] = __builtin_amdgcn_mfma_f32_16x16x32_bf16(al, bh[j], acc[i][j], 0, 0, 0);
            }
        }
    }
#pragma unroll
    for (int i = 0; i < 2; i++) {
#pragma unroll
        for (int r = 0; r < 4; r++) {
            int row = row0 + i * 16 + q * 4 + r;
            if (row < N_NODES) {
#pragma unroll
                for (int j = 0; j < 3; j++) {
                    int col = j * 16 + m;
                    if (col < N_CLASSES)
                        H2p[(size_t)row * 64 + col] = acc[i][j][r];
                }
            }
        }
    }
}

// ---------------------------------------------------------------------------
// agg2: one wave per dst node; 16 edges in flight (4 float4/lane), butterfly.
__global__ __launch_bounds__(256) void agg2_kernel(
    const int* __restrict__ offsets, const int* __restrict__ sorted_src,
    const float* __restrict__ H2p, const float* __restrict__ norm_dst,
    const float* __restrict__ b2, float* __restrict__ OUT) {
    int wid = (blockIdx.x * 256 + threadIdx.x) >> 6;
    int lane = threadIdx.x & 63;
    if (wid >= N_NODES) return;
    int start = offsets[wid], end = offsets[wid + 1];
    int quad = lane >> 4;
    int c4 = (lane & 15) * 4;
    bool active = c4 < N_CLASSES;
    float4 acc = make_float4(0.f, 0.f, 0.f, 0.f);
    int base = start;
    for (; base + 16 <= end; base += 16) {
        int e0 = sorted_src[base + quad];
        int e1 = sorted_src[base + 4 + quad];
        int e2 = sorted_src[base + 8 + quad];
        int e3 = sorted_src[base + 12 + quad];
        if (active) {
            float4 v0 = *(const float4*)&H2p[(size_t)e0 * 64 + c4];
            float4 v1 = *(const float4*)&H2p[(size_t)e1 * 64 + c4];
            float4 v2 = *(const float4*)&H2p[(size_t)e2 * 64 + c4];
            float4 v3 = *(const float4*)&H2p[(size_t)e3 * 64 + c4];
            acc.x += (v0.x + v1.x) + (v2.x + v3.x);
            acc.y += (v0.y + v1.y) + (v2.y + v3.y);
            acc.z += (v0.z + v1.z) + (v2.z + v3.z);
            acc.w += (v0.w + v1.w) + (v2.w + v3.w);
        }
    }
    for (; base + 4 <= end; base += 4) {
        int e = sorted_src[base + quad];
        if (active) {
            float4 v = *(const float4*)&H2p[(size_t)e * 64 + c4];
            acc.x += v.x; acc.y += v.y; acc.z += v.z; acc.w += v.w;
        }
    }
    int rem = end - base;
    if (quad < rem && active) {
        int e = sorted_src[base + quad];
        float4 v = *(const float4*)&H2p[(size_t)e * 64 + c4];
        acc.x += v.x; acc.y += v.y; acc.z += v.z; acc.w += v.w;
    }
    acc.x += __shfl_xor(acc.x, 16); acc.x += __shfl_xor(acc.x, 32);
    acc.y += __shfl_xor(acc.y, 16); acc.y += __shfl_xor(acc.y, 32);
    acc.z += __shfl_xor(acc.z, 16); acc.z += __shfl_xor(acc.z, 32);
    acc.w += __shfl_xor(acc.w, 16); acc.w += __shfl_xor(acc.w, 32);
    if (lane < 10) {
        float nd = norm_dst[wid];
        float4 b = *(const float4*)&b2[lane * 4];
        acc.x = acc.x * nd + b.x;
        acc.y = acc.y * nd + b.y;
        acc.z = acc.z * nd + b.z;
        acc.w = acc.w * nd + b.w;
        *(float4*)&OUT[(size_t)wid * N_CLASSES + lane * 4] = acc;
    }
}

// ---------------------------------------------------------------------------
extern "C" void kernel_launch(void* const* d_in, const int* in_sizes, int n_in,
                              void* d_out, int out_size, void* d_ws, size_t ws_size,
                              hipStream_t stream) {
    const float* X   = (const float*)d_in[0];
    const float* W1  = (const float*)d_in[1];
    const float* b1  = (const float*)d_in[2];
    const float* W2  = (const float*)d_in[3];
    const float* b2  = (const float*)d_in[4];
    const int*   src = (const int*)d_in[5];
    const int*   dst = (const int*)d_in[6];
    float* out = (float*)d_out;

    // workspace layout (4B units). regionA time-shared:
    //   phase 1: histD|histS|baseD|baseS|totD|totS      [dead after p3]
    //   phase 3: H2p f32 50000x64 (3.2M dwords)         [written at gemm2]
    // Hb now has its own region (written by megaA while phase-1 data live).
    float* norm_src   = (float*)d_ws;                     // 50000
    float* norm_dst   = norm_src + N_NODES;               // 50000
    int*   offsets    = (int*)(norm_dst + N_NODES);       // 50016 (incl pad)
    int*   bucket_base = offsets + N_NODES + 16;          // 800
    int*   srcb_base  = bucket_base + 800;                // 800
    unsigned int* edata = (unsigned int*)(srcb_base + 800);       // 1.6M
    unsigned char* srcv = (unsigned char*)(edata + N_EDGES);      // 400K dwords
    int*   sorted_src = (int*)(edata + N_EDGES) + 400000; // 1.6M
    int*   regionA    = sorted_src + N_EDGES;             // 3.2M dwords
    int*   histD      = regionA;
    int*   histS      = regionA + 625600;
    int*   baseD      = regionA + 1251200;
    int*   baseS      = regionA + 1876800;
    int*   totD       = regionA + 2502400;                // 800
    int*   totS       = regionA + 2503200;                // 800
    float* H2p        = (float*)regionA;                  // phase 3
    unsigned short* H1h = (unsigned short*)(regionA + 3200000);   // 50048x128 bf16
    unsigned short* H1l = H1h + (size_t)NROWPAD * N_HIDDEN;
    unsigned short* W1ch = H1l + (size_t)NROWPAD * N_HIDDEN;      // k-chunked 512*128
    unsigned short* W1cl = W1ch + IN_FEATS * N_HIDDEN;
    unsigned short* W2th = W1cl + IN_FEATS * N_HIDDEN;            // 48*128
    unsigned short* W2tl = W2th + 48 * 128;
    unsigned short* Hb   = W2tl + 48 * 128;               // 50000x128 bf16 (own region)

    setup_cvt<<<(IN_FEATS * N_HIDDEN + 48 * 128) / 256, 256, 0, stream>>>(
        W1, W2, W1ch, W1cl, W2th, W2tl);
    megaA<<<NBLK + NBKT, 256, 0, stream>>>(src, dst, histD, histS, X, W1ch, W1cl, Hb);
    p2_local<<<(NBKT + 3) / 4, 256, 0, stream>>>(histD, histS, baseD, baseS, totD, totS);
    p2_small<<<1, 1024, 0, stream>>>(totD, totS, bucket_base, srcb_base, offsets);
    p3_scatter<<<NBLK, 256, 0, stream>>>(src, dst, baseD, baseS, bucket_base, srcb_base,
                                         edata, srcv);
    p4_fused<<<NBKT, 256, 0, stream>>>(srcb_base, srcv, bucket_base, edata,
                                       offsets, norm_src, norm_dst, sorted_src);
    agg1_kernel<<<(N_NODES + 3) / 4, 256, 0, stream>>>(offsets, sorted_src, Hb, norm_dst,
                                                       norm_src, b1, H1h, H1l);
    gemm2_kernel<<<(N_NODES + 127) / 128, 256, 0, stream>>>(H1h, H1l, W2th, W2tl, H2p);
    agg2_kernel<<<(N_NODES + 3) / 4, 256, 0, stream>>>(offsets, sorted_src, H2p, norm_dst, b2, out);
}